// Round 12
// baseline (237.462 us; speedup 1.0000x reference)
//
#include <hip/hip_runtime.h>
#include <hip/hip_bf16.h>

using s8v = __attribute__((ext_vector_type(8))) short;   // 8 bf16 (4 VGPRs)
using f4v = __attribute__((ext_vector_type(4))) float;   // MFMA accumulator

__device__ __forceinline__ float bf2f(ushort v) { return __uint_as_float(((unsigned)v) << 16); }
__device__ __forceinline__ ushort f2bf(float x) {
  unsigned u = __float_as_uint(x);
  return (ushort)((u + 0x7fffu + ((u >> 16) & 1u)) >> 16);   // RNE, matches numpy
}

// |x - y| for 8 bf16 elems, result bf16, via v_cvt_pk_bf16_f32 (RNE)
__device__ __forceinline__ s8v absdiff_bf(s8v x, s8v y) {
  s8v d;
  #pragma unroll
  for (int q = 0; q < 4; ++q) {
    float f0 = fabsf(bf2f((ushort)x[2*q+0]) - bf2f((ushort)y[2*q+0]));
    float f1 = fabsf(bf2f((ushort)x[2*q+1]) - bf2f((ushort)y[2*q+1]));
    unsigned w;
    asm("v_cvt_pk_bf16_f32 %0, %1, %2" : "=v"(w) : "v"(f0), "v"(f1));
    d[2*q+0] = (short)(w & 0xffffu);
    d[2*q+1] = (short)(w >> 16);
  }
  return d;
}

#define BSH 9                    // 512 nodes per bucket
#define NPB 512
#define MAXB 256                 // covers N <= 131072
#define CHUNK 4096
#define HEAD_BLOCKS 1024         // persistent head grid (4 blocks/CU)

// ---------------- fused prep: cast h->bf16 + weight preps + per-chunk histogram ----------------
// Chunk histograms go to chunkHist[chunk][MAXB] via plain stores — no global
// atomics, no zeroing precondition (replaces the hipMemsetAsync + atomicAdd).

__global__ __launch_bounds__(256) void k_prep(
    const float* __restrict__ h, const float* __restrict__ W1,
    const float* __restrict__ Ws0, const float* __restrict__ Wn0,
    const float* __restrict__ Ws1, const float* __restrict__ Wn1,
    const int* __restrict__ dst,
    ushort* __restrict__ h_bf, ushort* __restrict__ w1t,
    ushort* __restrict__ tS0, ushort* __restrict__ tN0,
    ushort* __restrict__ tS1, ushort* __restrict__ tN1,
    int* __restrict__ chunkHist, int n8, int E, int nch)
{
  __shared__ int hh[MAXB];
  int t = threadIdx.x;
  int i = blockIdx.x * 256 + t;

  if (i < 4096) {            // layer weights -> bf16 transposed [j][k]
    int j = i >> 6, k = i & 63;
    int o = k * 64 + j;
    tS0[i] = f2bf(Ws0[o]);
    tN0[i] = f2bf(Wn0[o]);
    tS1[i] = f2bf(Ws1[o]);
    tN1[i] = f2bf(Wn1[o]);
  }
  if (i < 64 * 200) {        // W1 -> transposed bf16 [n][200], zero-padded
    int n = i / 200, k = i % 200;
    float v = (k < 192) ? W1[k * 64 + n] : 0.f;
    w1t[i] = f2bf(v);
  }
  if (i < n8) {              // h -> bf16, 8 elems/thread
    const float4* in4 = (const float4*)h;
    float4 va = in4[2 * i], vb = in4[2 * i + 1];
    s8v w;
    w[0] = (short)f2bf(va.x); w[1] = (short)f2bf(va.y);
    w[2] = (short)f2bf(va.z); w[3] = (short)f2bf(va.w);
    w[4] = (short)f2bf(vb.x); w[5] = (short)f2bf(vb.y);
    w[6] = (short)f2bf(vb.z); w[7] = (short)f2bf(vb.w);
    ((s8v*)h_bf)[i] = w;
  }
  if (blockIdx.x < (unsigned)nch) {   // bucket histogram for this chunk
    hh[t] = 0;
    __syncthreads();
    int base = blockIdx.x * CHUNK;
    #pragma unroll
    for (int k = 0; k < CHUNK / 256; ++k) {
      int e = base + k * 256 + t;
      if (e < E) atomicAdd(&hh[dst[e] >> BSH], 1);
    }
    __syncthreads();
    chunkHist[blockIdx.x * MAXB + t] = hh[t];
  }
}

// ---------------- phase 2: sum chunk histograms + scan -> base & cursor ----------------

__global__ __launch_bounds__(256) void k_bscan(const int* __restrict__ chunkHist,
                                               int* __restrict__ bucketBase,
                                               int* __restrict__ bucketCursor,
                                               int* __restrict__ row_ptr,
                                               int B, int N, int E, int nch) {
  __shared__ int sh[MAXB];
  int t = threadIdx.x;
  int v = 0;
  for (int c = 0; c < nch; ++c) v += chunkHist[c * MAXB + t];
  sh[t] = v;
  __syncthreads();
  for (int off = 1; off < MAXB; off <<= 1) {
    int y = (t >= off) ? sh[t - off] : 0;
    __syncthreads();
    sh[t] += y;
    __syncthreads();
  }
  int excl = sh[t] - v;
  if (t < B) { bucketBase[t] = excl; bucketCursor[t] = excl; }
  if (t == 0) { bucketBase[B] = E; row_ptr[N] = E; }
}

// ---------------- phase 3: partition edges into bucket-grouped staging ----------------

__global__ __launch_bounds__(256) void k_part(
    const int* __restrict__ src, const int* __restrict__ dst,
    int* __restrict__ bucketCursor, int2* __restrict__ stag, int E)
{
  __shared__ int hh[MAXB];     // local hist
  __shared__ int sc[MAXB];     // local exclusive scan
  __shared__ int cur[MAXB];    // placement cursor
  __shared__ int gb[MAXB];     // global base for this block's run
  __shared__ int2 pairs[CHUNK];

  int t = threadIdx.x;
  int base = blockIdx.x * CHUNK;
  int M = E - base; if (M > CHUNK) M = CHUNK;

  int es[CHUNK / 256], ed[CHUNK / 256];
  #pragma unroll
  for (int k = 0; k < CHUNK / 256; ++k) {
    int e = base + k * 256 + t;
    if (e < E) { es[k] = src[e]; ed[k] = dst[e]; } else { ed[k] = -1; }
  }

  hh[t] = 0;
  __syncthreads();
  #pragma unroll
  for (int k = 0; k < CHUNK / 256; ++k)
    if (ed[k] >= 0) atomicAdd(&hh[ed[k] >> BSH], 1);
  __syncthreads();

  // exclusive scan of hh[0..256) with 256 threads
  int v = hh[t];
  sc[t] = v;
  __syncthreads();
  for (int off = 1; off < MAXB; off <<= 1) {
    int y = (t >= off) ? sc[t - off] : 0;
    __syncthreads();
    sc[t] += y;
    __syncthreads();
  }
  int excl = sc[t] - v;
  sc[t] = excl;
  cur[t] = excl;
  if (v) gb[t] = atomicAdd(&bucketCursor[t], v);
  __syncthreads();

  // place pairs bucket-major into LDS
  #pragma unroll
  for (int k = 0; k < CHUNK / 256; ++k)
    if (ed[k] >= 0) {
      int b = ed[k] >> BSH;
      int pos = atomicAdd(&cur[b], 1);
      pairs[pos] = make_int2(es[k], ed[k]);
    }
  __syncthreads();

  // write out: slot s of bucket b goes to stag[gb[b] + s - sc[b]]
  for (int s = t; s < M; s += 256) {
    int2 pr = pairs[s];
    int b = pr.y >> BSH;
    stag[gb[b] + s - sc[b]] = pr;
  }
}

// ---------------- phase 4: per-bucket CSR finalize ----------------

__global__ __launch_bounds__(512) void k_csr_bucket(
    const int2* __restrict__ stag, const int* __restrict__ bucketBase,
    int* __restrict__ row_ptr, int* __restrict__ csr_src, int N)
{
  __shared__ int dh[NPB], db[NPB], dc[NPB];
  int t = threadIdx.x;
  int b = blockIdx.x;
  int n0 = b << BSH;
  int nn = N - n0; if (nn > NPB) nn = NPB;
  int estart = bucketBase[b], eend = bucketBase[b + 1];

  dh[t] = 0;
  __syncthreads();
  for (int e = estart + t; e < eend; e += 512)
    atomicAdd(&dh[stag[e].y - n0], 1);
  __syncthreads();
  int v = dh[t];
  db[t] = v;
  __syncthreads();
  for (int off = 1; off < NPB; off <<= 1) {
    int y = (t >= off) ? db[t - off] : 0;
    __syncthreads();
    db[t] += y;
    __syncthreads();
  }
  int excl = db[t] - v;
  if (t < nn) row_ptr[n0 + t] = estart + excl;
  dc[t] = excl;
  __syncthreads();
  for (int e = estart + t; e < eend; e += 512) {
    int2 pr = stag[e];
    int d = pr.y - n0;
    int pos = estart + atomicAdd(&dc[d], 1);
    csr_src[pos] = pr.x;
  }
}

// ---------------- aggregation: wave-per-node, 2x unrolled ----------------

__global__ __launch_bounds__(256) void k_agg_bf(
    const ushort* __restrict__ fb, const int* __restrict__ rp,
    const int* __restrict__ csrc, ushort* __restrict__ agg, int N)
{
  int lane = threadIdx.x & 63;
  int node = (blockIdx.x * 256 + threadIdx.x) >> 6;
  if (node >= N) return;
  int g  = lane >> 3;
  int c8 = (lane & 7) * 8;
  int e0 = rp[node], e1 = rp[node + 1];
  int len = e1 - e0;
  float a0=0.f,a1=0.f,a2=0.f,a3=0.f,a4=0.f,a5=0.f,a6=0.f,a7=0.f;
  int nfull = len >> 3;
  int it = 0;
  int e = e0;
  for (; it + 2 <= nfull; it += 2, e += 16) {
    int sA = csrc[e + g];
    int sB = csrc[e + 8 + g];
    s8v va = *(const s8v*)(fb + (size_t)sA * 64 + c8);
    s8v vb = *(const s8v*)(fb + (size_t)sB * 64 + c8);
    a0 += bf2f((ushort)va[0]); a1 += bf2f((ushort)va[1]);
    a2 += bf2f((ushort)va[2]); a3 += bf2f((ushort)va[3]);
    a4 += bf2f((ushort)va[4]); a5 += bf2f((ushort)va[5]);
    a6 += bf2f((ushort)va[6]); a7 += bf2f((ushort)va[7]);
    a0 += bf2f((ushort)vb[0]); a1 += bf2f((ushort)vb[1]);
    a2 += bf2f((ushort)vb[2]); a3 += bf2f((ushort)vb[3]);
    a4 += bf2f((ushort)vb[4]); a5 += bf2f((ushort)vb[5]);
    a6 += bf2f((ushort)vb[6]); a7 += bf2f((ushort)vb[7]);
  }
  if (it < nfull) {
    int s = csrc[e + g];
    s8v vv = *(const s8v*)(fb + (size_t)s * 64 + c8);
    a0 += bf2f((ushort)vv[0]); a1 += bf2f((ushort)vv[1]);
    a2 += bf2f((ushort)vv[2]); a3 += bf2f((ushort)vv[3]);
    a4 += bf2f((ushort)vv[4]); a5 += bf2f((ushort)vv[5]);
    a6 += bf2f((ushort)vv[6]); a7 += bf2f((ushort)vv[7]);
    e += 8;
  }
  if (e + g < e1) {
    int s = csrc[e + g];
    s8v vv = *(const s8v*)(fb + (size_t)s * 64 + c8);
    a0 += bf2f((ushort)vv[0]); a1 += bf2f((ushort)vv[1]);
    a2 += bf2f((ushort)vv[2]); a3 += bf2f((ushort)vv[3]);
    a4 += bf2f((ushort)vv[4]); a5 += bf2f((ushort)vv[5]);
    a6 += bf2f((ushort)vv[6]); a7 += bf2f((ushort)vv[7]);
  }
  a0 += __shfl_xor(a0, 8); a0 += __shfl_xor(a0, 16); a0 += __shfl_xor(a0, 32);
  a1 += __shfl_xor(a1, 8); a1 += __shfl_xor(a1, 16); a1 += __shfl_xor(a1, 32);
  a2 += __shfl_xor(a2, 8); a2 += __shfl_xor(a2, 16); a2 += __shfl_xor(a2, 32);
  a3 += __shfl_xor(a3, 8); a3 += __shfl_xor(a3, 16); a3 += __shfl_xor(a3, 32);
  a4 += __shfl_xor(a4, 8); a4 += __shfl_xor(a4, 16); a4 += __shfl_xor(a4, 32);
  a5 += __shfl_xor(a5, 8); a5 += __shfl_xor(a5, 16); a5 += __shfl_xor(a5, 32);
  a6 += __shfl_xor(a6, 8); a6 += __shfl_xor(a6, 16); a6 += __shfl_xor(a6, 32);
  a7 += __shfl_xor(a7, 8); a7 += __shfl_xor(a7, 16); a7 += __shfl_xor(a7, 32);
  if (g == 0) {
    float inv = 1.f / (float)(len > 0 ? len : 1);
    s8v o;
    o[0] = (short)f2bf(a0 * inv); o[1] = (short)f2bf(a1 * inv);
    o[2] = (short)f2bf(a2 * inv); o[3] = (short)f2bf(a3 * inv);
    o[4] = (short)f2bf(a4 * inv); o[5] = (short)f2bf(a5 * inv);
    o[6] = (short)f2bf(a6 * inv); o[7] = (short)f2bf(a7 * inv);
    *(s8v*)(agg + (size_t)node * 64 + c8) = o;
  }
}

// ---------------- layer transform via MFMA: 32 nodes/wave ----------------

__global__ __launch_bounds__(256) void k_xform_mfma(
    const ushort* __restrict__ fb, const ushort* __restrict__ ab,
    const ushort* __restrict__ wtS, const ushort* __restrict__ wtN,
    const float* __restrict__ bias, ushort* __restrict__ outb, int N)
{
  int lane = threadIdx.x & 63;
  int wid  = threadIdx.x >> 6;
  int wbase = blockIdx.x * 128 + wid * 32;
  if (wbase >= N) return;
  int lrow = lane & 15;
  int lkg  = lane >> 4;

  // B-fragments: L1-resident, loaded once per wave
  s8v bS[4][2], bN[4][2];
  #pragma unroll
  for (int nt = 0; nt < 4; ++nt) {
    #pragma unroll
    for (int ks = 0; ks < 2; ++ks) {
      int o = (nt * 16 + lrow) * 64 + ks * 32 + lkg * 8;
      bS[nt][ks] = *(const s8v*)(wtS + o);
      bN[nt][ks] = *(const s8v*)(wtN + o);
    }
  }

  f4v acc[2][4];
  #pragma unroll
  for (int a = 0; a < 2; ++a)
    #pragma unroll
    for (int b = 0; b < 4; ++b)
      acc[a][b] = (f4v){0.f, 0.f, 0.f, 0.f};

  #pragma unroll
  for (int pt = 0; pt < 2; ++pt) {
    int node = wbase + pt * 16 + lrow;
    int nc = (node < N) ? node : (N - 1);
    const ushort* fr = fb + (size_t)nc * 64 + lkg * 8;
    const ushort* ar = ab + (size_t)nc * 64 + lkg * 8;
    s8v f0 = *(const s8v*)(fr);
    s8v f1 = *(const s8v*)(fr + 32);
    s8v g0 = *(const s8v*)(ar);
    s8v g1 = *(const s8v*)(ar + 32);
    #pragma unroll
    for (int nt = 0; nt < 4; ++nt) {
      acc[pt][nt] = __builtin_amdgcn_mfma_f32_16x16x32_bf16(f0, bS[nt][0], acc[pt][nt], 0, 0, 0);
      acc[pt][nt] = __builtin_amdgcn_mfma_f32_16x16x32_bf16(f1, bS[nt][1], acc[pt][nt], 0, 0, 0);
      acc[pt][nt] = __builtin_amdgcn_mfma_f32_16x16x32_bf16(g0, bN[nt][0], acc[pt][nt], 0, 0, 0);
      acc[pt][nt] = __builtin_amdgcn_mfma_f32_16x16x32_bf16(g1, bN[nt][1], acc[pt][nt], 0, 0, 0);
    }
  }

  float bv[4];
  #pragma unroll
  for (int nt = 0; nt < 4; ++nt) bv[nt] = bias[nt * 16 + lrow];

  #pragma unroll
  for (int pt = 0; pt < 2; ++pt) {
    #pragma unroll
    for (int r = 0; r < 4; ++r) {
      int node = wbase + pt * 16 + lkg * 4 + r;
      if (node < N) {
        ushort* orow = outb + (size_t)node * 64;
        #pragma unroll
        for (int nt = 0; nt < 4; ++nt) {
          float z = fmaxf(acc[pt][nt][r] + bv[nt], 0.f);
          orow[nt * 16 + lrow] = f2bf(z);
        }
      }
    }
  }
}

// ---------------- head via MFMA: persistent blocks, W staged ONCE per block ----------------

__global__ __launch_bounds__(256) void k_head_mfma(
    const ushort* __restrict__ hb, const int* __restrict__ x1, const int* __restrict__ x2,
    const ushort* __restrict__ w1t, const float* __restrict__ bl1,
    const float* __restrict__ W2, const float* __restrict__ bl2,
    float* __restrict__ out, int P)
{
  __shared__ __align__(16) ushort sW[64 * 200];
  __shared__ float sW2[128];
  __shared__ float sb1[64];
  __shared__ float sb2[2];
  {
    const float4* srcv = (const float4*)w1t;   // 12800 ushort = 1600 float4
    float4* dstv = (float4*)sW;
    for (int i = threadIdx.x; i < 1600; i += 256) dstv[i] = srcv[i];
    if (threadIdx.x < 128) sW2[threadIdx.x] = W2[threadIdx.x];
    if (threadIdx.x < 64)  sb1[threadIdx.x] = bl1[threadIdx.x];
    if (threadIdx.x < 2)   sb2[threadIdx.x] = bl2[threadIdx.x];
  }
  __syncthreads();

  int lane = threadIdx.x & 63;
  int wid  = threadIdx.x >> 6;
  int lrow = lane & 15;
  int lkg  = lane >> 4;

  float b1v[4], w20v[4], w21v[4];
  #pragma unroll
  for (int nt = 0; nt < 4; ++nt) {
    int n = nt * 16 + lrow;
    b1v[nt] = sb1[n];
    w20v[nt] = sW2[2 * n + 0];
    w21v[nt] = sW2[2 * n + 1];
  }
  float bb0 = sb2[0], bb1 = sb2[1];

  int nTiles = (P + 127) / 128;
  for (int tile = blockIdx.x; tile < nTiles; tile += gridDim.x) {
    int wbase = tile * 128 + wid * 32;   // 32 pairs per wave
    if (wbase >= P) continue;

    // pair gathers (clamped)
    int pa = wbase + lrow;
    int pb = wbase + 16 + lrow;
    int pca = (pa < P) ? pa : (P - 1);
    int pcb = (pb < P) ? pb : (P - 1);
    int i1a = x1[pca], i2a = x2[pca];
    int i1b = x1[pcb], i2b = x2[pcb];
    const ushort* r1a = hb + (size_t)i1a * 64 + lkg * 8;
    const ushort* r2a = hb + (size_t)i2a * 64 + lkg * 8;
    const ushort* r1b = hb + (size_t)i1b * 64 + lkg * 8;
    const ushort* r2b = hb + (size_t)i2b * 64 + lkg * 8;
    s8v a1a0 = *(const s8v*)(r1a);
    s8v a1a1 = *(const s8v*)(r1a + 32);
    s8v a2a0 = *(const s8v*)(r2a);
    s8v a2a1 = *(const s8v*)(r2a + 32);
    s8v a1b0 = *(const s8v*)(r1b);
    s8v a1b1 = *(const s8v*)(r1b + 32);
    s8v a2b0 = *(const s8v*)(r2b);
    s8v a2b1 = *(const s8v*)(r2b + 32);

    s8v da0 = absdiff_bf(a1a0, a2a0);
    s8v da1 = absdiff_bf(a1a1, a2a1);
    s8v db0 = absdiff_bf(a1b0, a2b0);
    s8v db1 = absdiff_bf(a1b1, a2b1);

    f4v acc[2][4];
    #pragma unroll
    for (int a = 0; a < 2; ++a)
      #pragma unroll
      for (int b = 0; b < 4; ++b)
        acc[a][b] = (f4v){0.f, 0.f, 0.f, 0.f};

    #pragma unroll
    for (int nt = 0; nt < 4; ++nt) {
      const ushort* bw = &sW[(nt * 16 + lrow) * 200 + lkg * 8];
      s8v b1_0 = *(const s8v*)(bw + 0);
      s8v b2_0 = *(const s8v*)(bw + 64);
      s8v b3_0 = *(const s8v*)(bw + 128);
      acc[0][nt] = __builtin_amdgcn_mfma_f32_16x16x32_bf16(a1a0, b1_0, acc[0][nt], 0, 0, 0);
      acc[0][nt] = __builtin_amdgcn_mfma_f32_16x16x32_bf16(a2a0, b2_0, acc[0][nt], 0, 0, 0);
      acc[0][nt] = __builtin_amdgcn_mfma_f32_16x16x32_bf16(da0,  b3_0, acc[0][nt], 0, 0, 0);
      acc[1][nt] = __builtin_amdgcn_mfma_f32_16x16x32_bf16(a1b0, b1_0, acc[1][nt], 0, 0, 0);
      acc[1][nt] = __builtin_amdgcn_mfma_f32_16x16x32_bf16(a2b0, b2_0, acc[1][nt], 0, 0, 0);
      acc[1][nt] = __builtin_amdgcn_mfma_f32_16x16x32_bf16(db0,  b3_0, acc[1][nt], 0, 0, 0);
      s8v b1_1 = *(const s8v*)(bw + 32);
      s8v b2_1 = *(const s8v*)(bw + 96);
      s8v b3_1 = *(const s8v*)(bw + 160);
      acc[0][nt] = __builtin_amdgcn_mfma_f32_16x16x32_bf16(a1a1, b1_1, acc[0][nt], 0, 0, 0);
      acc[0][nt] = __builtin_amdgcn_mfma_f32_16x16x32_bf16(a2a1, b2_1, acc[0][nt], 0, 0, 0);
      acc[0][nt] = __builtin_amdgcn_mfma_f32_16x16x32_bf16(da1,  b3_1, acc[0][nt], 0, 0, 0);
      acc[1][nt] = __builtin_amdgcn_mfma_f32_16x16x32_bf16(a1b1, b1_1, acc[1][nt], 0, 0, 0);
      acc[1][nt] = __builtin_amdgcn_mfma_f32_16x16x32_bf16(a2b1, b2_1, acc[1][nt], 0, 0, 0);
      acc[1][nt] = __builtin_amdgcn_mfma_f32_16x16x32_bf16(db1,  b3_1, acc[1][nt], 0, 0, 0);
    }

    #pragma unroll
    for (int pt = 0; pt < 2; ++pt) {
      #pragma unroll
      for (int r = 0; r < 4; ++r) {
        float p0 = 0.f, p1 = 0.f;
        #pragma unroll
        for (int nt = 0; nt < 4; ++nt) {
          float z = fmaxf(acc[pt][nt][r] + b1v[nt], 0.f);
          p0 += z * w20v[nt];
          p1 += z * w21v[nt];
        }
        p0 += __shfl_xor(p0, 1); p1 += __shfl_xor(p1, 1);
        p0 += __shfl_xor(p0, 2); p1 += __shfl_xor(p1, 2);
        p0 += __shfl_xor(p0, 4); p1 += __shfl_xor(p1, 4);
        p0 += __shfl_xor(p0, 8); p1 += __shfl_xor(p1, 8);
        int pair = wbase + pt * 16 + lkg * 4 + r;
        if (lrow == 0 && pair < P) {
          float2 o = make_float2(p0 + bb0, p1 + bb1);
          *(float2*)(out + 2 * (size_t)pair) = o;
        }
      }
    }
  }
}

// ---------------- launch ----------------

extern "C" void kernel_launch(void* const* d_in, const int* in_sizes, int n_in,
                              void* d_out, int out_size, void* d_ws, size_t ws_size,
                              hipStream_t stream)
{
  (void)n_in; (void)out_size; (void)ws_size;
  const float* h   = (const float*)d_in[0];
  const int*   src = (const int*)d_in[1];
  const int*   dst = (const int*)d_in[2];
  const int*   x1  = (const int*)d_in[3];
  const int*   x2  = (const int*)d_in[4];
  const float* Ws0 = (const float*)d_in[5];
  const float* Wn0 = (const float*)d_in[6];
  const float* b0  = (const float*)d_in[7];
  const float* Ws1 = (const float*)d_in[8];
  const float* Wn1 = (const float*)d_in[9];
  const float* b1  = (const float*)d_in[10];
  const float* W1  = (const float*)d_in[11];
  const float* bl1 = (const float*)d_in[12];
  const float* W2  = (const float*)d_in[13];
  const float* bl2 = (const float*)d_in[14];

  const int N = in_sizes[0] / 64;
  const int E = in_sizes[1];
  const int P = in_sizes[3];
  const int B = (N + NPB - 1) >> BSH;
  float* out = (float*)d_out;

  const int NCH = (E + CHUNK - 1) / CHUNK;
  const int n8  = N * 64 / 8;

  char* ws = (char*)d_ws;
  size_t off = 0;
  auto carve = [&](size_t bytes) {
    char* p = ws + off;
    off = (off + bytes + 255) & ~(size_t)255;
    return p;
  };
  int*    row_ptr      = (int*)carve((size_t)(N + 1) * 4);
  int*    chunkHist    = (int*)carve((size_t)NCH * MAXB * 4);
  int*    bucketBase   = (int*)carve((MAXB + 1) * 4);
  int*    bucketCursor = (int*)carve(MAXB * 4);
  int*    csr_src  = (int*)carve((size_t)E * 4);
  ushort* h_bf     = (ushort*)carve((size_t)N * 64 * 2);
  ushort* m1       = (ushort*)carve((size_t)N * 64 * 2);
  ushort* m2       = (ushort*)carve((size_t)N * 64 * 2);
  int2*   stag     = (int2*)carve((size_t)E * 8);
  ushort* aggb     = (ushort*)carve((size_t)N * 64 * 2);
  ushort* w1t      = (ushort*)carve(64 * 200 * 2);
  ushort* wtS0     = (ushort*)carve(4096 * 2);
  ushort* wtN0     = (ushort*)carve(4096 * 2);
  ushort* wtS1     = (ushort*)carve(4096 * 2);
  ushort* wtN1     = (ushort*)carve(4096 * 2);

  k_prep<<<(n8 + 255) / 256, 256, 0, stream>>>(h, W1, Ws0, Wn0, Ws1, Wn1, dst,
                                               h_bf, w1t, wtS0, wtN0, wtS1, wtN1,
                                               chunkHist, n8, E, NCH);
  k_bscan<<<1, MAXB, 0, stream>>>(chunkHist, bucketBase, bucketCursor, row_ptr, B, N, E, NCH);
  k_part <<<NCH, 256, 0, stream>>>(src, dst, bucketCursor, stag, E);
  k_csr_bucket<<<B, NPB, 0, stream>>>(stag, bucketBase, row_ptr, csr_src, N);

  const int nbW = (N + 3) / 4;
  const int nbX = (N + 127) / 128;   // 128 nodes per block (32/wave)

  k_agg_bf<<<nbW, 256, 0, stream>>>(h_bf, row_ptr, csr_src, aggb, N);
  k_xform_mfma<<<nbX, 256, 0, stream>>>(h_bf, aggb, wtS0, wtN0, b0, m1, N);
  k_agg_bf<<<nbW, 256, 0, stream>>>(m1, row_ptr, csr_src, aggb, N);
  k_xform_mfma<<<nbX, 256, 0, stream>>>(m1, aggb, wtS1, wtN1, b1, m2, N);

  const int nTiles = (P + 127) / 128;
  const int nbP = (nTiles < HEAD_BLOCKS) ? nTiles : HEAD_BLOCKS;
  k_head_mfma<<<nbP, 256, 0, stream>>>(m2, x1, x2, w1t, bl1, W2, bl2, out, P);
}

// Round 13
// 188.087 us; speedup vs baseline: 1.2625x; 1.2625x over previous
//
#include <hip/hip_runtime.h>
#include <hip/hip_bf16.h>

using s8v = __attribute__((ext_vector_type(8))) short;   // 8 bf16 (4 VGPRs)
using f4v = __attribute__((ext_vector_type(4))) float;   // MFMA accumulator

__device__ __forceinline__ float bf2f(ushort v) { return __uint_as_float(((unsigned)v) << 16); }
__device__ __forceinline__ ushort f2bf(float x) {
  unsigned u = __float_as_uint(x);
  return (ushort)((u + 0x7fffu + ((u >> 16) & 1u)) >> 16);   // RNE, matches numpy
}

// |x - y| for 8 bf16 elems, result bf16, via v_cvt_pk_bf16_f32 (RNE)
__device__ __forceinline__ s8v absdiff_bf(s8v x, s8v y) {
  s8v d;
  #pragma unroll
  for (int q = 0; q < 4; ++q) {
    float f0 = fabsf(bf2f((ushort)x[2*q+0]) - bf2f((ushort)y[2*q+0]));
    float f1 = fabsf(bf2f((ushort)x[2*q+1]) - bf2f((ushort)y[2*q+1]));
    unsigned w;
    asm("v_cvt_pk_bf16_f32 %0, %1, %2" : "=v"(w) : "v"(f0), "v"(f1));
    d[2*q+0] = (short)(w & 0xffffu);
    d[2*q+1] = (short)(w >> 16);
  }
  return d;
}

#define BSH 9                    // 512 nodes per bucket
#define NPB 512
#define MAXB 256                 // covers N <= 131072
#define CHUNK 4096
#define HEAD_BLOCKS 1024         // persistent head grid (4 blocks/CU)

// ---------------- fused prep: cast h->bf16 + weight preps + per-chunk histogram ----------------
// Chunk histograms go to chunkHist[chunk][MAXB] via plain stores — no global
// atomics, no zeroing precondition.

__global__ __launch_bounds__(256) void k_prep(
    const float* __restrict__ h, const float* __restrict__ W1,
    const float* __restrict__ Ws0, const float* __restrict__ Wn0,
    const float* __restrict__ Ws1, const float* __restrict__ Wn1,
    const int* __restrict__ dst,
    ushort* __restrict__ h_bf, ushort* __restrict__ w1t,
    ushort* __restrict__ tS0, ushort* __restrict__ tN0,
    ushort* __restrict__ tS1, ushort* __restrict__ tN1,
    int* __restrict__ chunkHist, int n8, int E, int nch)
{
  __shared__ int hh[MAXB];
  int t = threadIdx.x;
  int i = blockIdx.x * 256 + t;

  if (i < 4096) {            // layer weights -> bf16 transposed [j][k]
    int j = i >> 6, k = i & 63;
    int o = k * 64 + j;
    tS0[i] = f2bf(Ws0[o]);
    tN0[i] = f2bf(Wn0[o]);
    tS1[i] = f2bf(Ws1[o]);
    tN1[i] = f2bf(Wn1[o]);
  }
  if (i < 64 * 200) {        // W1 -> transposed bf16 [n][200], zero-padded
    int n = i / 200, k = i % 200;
    float v = (k < 192) ? W1[k * 64 + n] : 0.f;
    w1t[i] = f2bf(v);
  }
  if (i < n8) {              // h -> bf16, 8 elems/thread
    const float4* in4 = (const float4*)h;
    float4 va = in4[2 * i], vb = in4[2 * i + 1];
    s8v w;
    w[0] = (short)f2bf(va.x); w[1] = (short)f2bf(va.y);
    w[2] = (short)f2bf(va.z); w[3] = (short)f2bf(va.w);
    w[4] = (short)f2bf(vb.x); w[5] = (short)f2bf(vb.y);
    w[6] = (short)f2bf(vb.z); w[7] = (short)f2bf(vb.w);
    ((s8v*)h_bf)[i] = w;
  }
  if (blockIdx.x < (unsigned)nch) {   // bucket histogram for this chunk
    hh[t] = 0;
    __syncthreads();
    int base = blockIdx.x * CHUNK;
    #pragma unroll
    for (int k = 0; k < CHUNK / 256; ++k) {
      int e = base + k * 256 + t;
      if (e < E) atomicAdd(&hh[dst[e] >> BSH], 1);
    }
    __syncthreads();
    chunkHist[blockIdx.x * MAXB + t] = hh[t];
  }
}

// ---------------- phase 1b: parallel reduction of chunk histograms ----------------
// One block per bucket; thread t sums chunks t, t+256, ... (all loads in
// flight in parallel). Replaces R12's 391-deep serial chain in k_bscan.

__global__ __launch_bounds__(256) void k_hsum(const int* __restrict__ chunkHist,
                                              int* __restrict__ bucketCnt, int nch) {
  __shared__ int sh[256];
  int b = blockIdx.x;
  int t = threadIdx.x;
  int v = 0;
  for (int c = t; c < nch; c += 256) v += chunkHist[c * MAXB + b];
  sh[t] = v;
  __syncthreads();
  for (int o = 128; o > 0; o >>= 1) {
    if (t < o) sh[t] += sh[t + o];
    __syncthreads();
  }
  if (t == 0) bucketCnt[b] = sh[0];
}

// ---------------- phase 2: scan buckets -> base & cursor ----------------

__global__ __launch_bounds__(256) void k_bscan(const int* __restrict__ bucketCnt,
                                               int* __restrict__ bucketBase,
                                               int* __restrict__ bucketCursor,
                                               int* __restrict__ row_ptr,
                                               int B, int N, int E) {
  __shared__ int sh[MAXB];
  int t = threadIdx.x;
  int v = (t < B) ? bucketCnt[t] : 0;
  sh[t] = v;
  __syncthreads();
  for (int off = 1; off < MAXB; off <<= 1) {
    int y = (t >= off) ? sh[t - off] : 0;
    __syncthreads();
    sh[t] += y;
    __syncthreads();
  }
  int excl = sh[t] - v;
  if (t < B) { bucketBase[t] = excl; bucketCursor[t] = excl; }
  if (t == 0) { bucketBase[B] = E; row_ptr[N] = E; }
}

// ---------------- phase 3: partition edges into bucket-grouped staging ----------------

__global__ __launch_bounds__(256) void k_part(
    const int* __restrict__ src, const int* __restrict__ dst,
    int* __restrict__ bucketCursor, int2* __restrict__ stag, int E)
{
  __shared__ int hh[MAXB];     // local hist
  __shared__ int sc[MAXB];     // local exclusive scan
  __shared__ int cur[MAXB];    // placement cursor
  __shared__ int gb[MAXB];     // global base for this block's run
  __shared__ int2 pairs[CHUNK];

  int t = threadIdx.x;
  int base = blockIdx.x * CHUNK;
  int M = E - base; if (M > CHUNK) M = CHUNK;

  int es[CHUNK / 256], ed[CHUNK / 256];
  #pragma unroll
  for (int k = 0; k < CHUNK / 256; ++k) {
    int e = base + k * 256 + t;
    if (e < E) { es[k] = src[e]; ed[k] = dst[e]; } else { ed[k] = -1; }
  }

  hh[t] = 0;
  __syncthreads();
  #pragma unroll
  for (int k = 0; k < CHUNK / 256; ++k)
    if (ed[k] >= 0) atomicAdd(&hh[ed[k] >> BSH], 1);
  __syncthreads();

  // exclusive scan of hh[0..256) with 256 threads
  int v = hh[t];
  sc[t] = v;
  __syncthreads();
  for (int off = 1; off < MAXB; off <<= 1) {
    int y = (t >= off) ? sc[t - off] : 0;
    __syncthreads();
    sc[t] += y;
    __syncthreads();
  }
  int excl = sc[t] - v;
  sc[t] = excl;
  cur[t] = excl;
  if (v) gb[t] = atomicAdd(&bucketCursor[t], v);
  __syncthreads();

  // place pairs bucket-major into LDS
  #pragma unroll
  for (int k = 0; k < CHUNK / 256; ++k)
    if (ed[k] >= 0) {
      int b = ed[k] >> BSH;
      int pos = atomicAdd(&cur[b], 1);
      pairs[pos] = make_int2(es[k], ed[k]);
    }
  __syncthreads();

  // write out: slot s of bucket b goes to stag[gb[b] + s - sc[b]]
  for (int s = t; s < M; s += 256) {
    int2 pr = pairs[s];
    int b = pr.y >> BSH;
    stag[gb[b] + s - sc[b]] = pr;
  }
}

// ---------------- phase 4: per-bucket CSR finalize ----------------

__global__ __launch_bounds__(512) void k_csr_bucket(
    const int2* __restrict__ stag, const int* __restrict__ bucketBase,
    int* __restrict__ row_ptr, int* __restrict__ csr_src, int N)
{
  __shared__ int dh[NPB], db[NPB], dc[NPB];
  int t = threadIdx.x;
  int b = blockIdx.x;
  int n0 = b << BSH;
  int nn = N - n0; if (nn > NPB) nn = NPB;
  int estart = bucketBase[b], eend = bucketBase[b + 1];

  dh[t] = 0;
  __syncthreads();
  for (int e = estart + t; e < eend; e += 512)
    atomicAdd(&dh[stag[e].y - n0], 1);
  __syncthreads();
  int v = dh[t];
  db[t] = v;
  __syncthreads();
  for (int off = 1; off < NPB; off <<= 1) {
    int y = (t >= off) ? db[t - off] : 0;
    __syncthreads();
    db[t] += y;
    __syncthreads();
  }
  int excl = db[t] - v;
  if (t < nn) row_ptr[n0 + t] = estart + excl;
  dc[t] = excl;
  __syncthreads();
  for (int e = estart + t; e < eend; e += 512) {
    int2 pr = stag[e];
    int d = pr.y - n0;
    int pos = estart + atomicAdd(&dc[d], 1);
    csr_src[pos] = pr.x;
  }
}

// ---------------- aggregation: wave-per-node, 2x unrolled ----------------

__global__ __launch_bounds__(256) void k_agg_bf(
    const ushort* __restrict__ fb, const int* __restrict__ rp,
    const int* __restrict__ csrc, ushort* __restrict__ agg, int N)
{
  int lane = threadIdx.x & 63;
  int node = (blockIdx.x * 256 + threadIdx.x) >> 6;
  if (node >= N) return;
  int g  = lane >> 3;
  int c8 = (lane & 7) * 8;
  int e0 = rp[node], e1 = rp[node + 1];
  int len = e1 - e0;
  float a0=0.f,a1=0.f,a2=0.f,a3=0.f,a4=0.f,a5=0.f,a6=0.f,a7=0.f;
  int nfull = len >> 3;
  int it = 0;
  int e = e0;
  for (; it + 2 <= nfull; it += 2, e += 16) {
    int sA = csrc[e + g];
    int sB = csrc[e + 8 + g];
    s8v va = *(const s8v*)(fb + (size_t)sA * 64 + c8);
    s8v vb = *(const s8v*)(fb + (size_t)sB * 64 + c8);
    a0 += bf2f((ushort)va[0]); a1 += bf2f((ushort)va[1]);
    a2 += bf2f((ushort)va[2]); a3 += bf2f((ushort)va[3]);
    a4 += bf2f((ushort)va[4]); a5 += bf2f((ushort)va[5]);
    a6 += bf2f((ushort)va[6]); a7 += bf2f((ushort)va[7]);
    a0 += bf2f((ushort)vb[0]); a1 += bf2f((ushort)vb[1]);
    a2 += bf2f((ushort)vb[2]); a3 += bf2f((ushort)vb[3]);
    a4 += bf2f((ushort)vb[4]); a5 += bf2f((ushort)vb[5]);
    a6 += bf2f((ushort)vb[6]); a7 += bf2f((ushort)vb[7]);
  }
  if (it < nfull) {
    int s = csrc[e + g];
    s8v vv = *(const s8v*)(fb + (size_t)s * 64 + c8);
    a0 += bf2f((ushort)vv[0]); a1 += bf2f((ushort)vv[1]);
    a2 += bf2f((ushort)vv[2]); a3 += bf2f((ushort)vv[3]);
    a4 += bf2f((ushort)vv[4]); a5 += bf2f((ushort)vv[5]);
    a6 += bf2f((ushort)vv[6]); a7 += bf2f((ushort)vv[7]);
    e += 8;
  }
  if (e + g < e1) {
    int s = csrc[e + g];
    s8v vv = *(const s8v*)(fb + (size_t)s * 64 + c8);
    a0 += bf2f((ushort)vv[0]); a1 += bf2f((ushort)vv[1]);
    a2 += bf2f((ushort)vv[2]); a3 += bf2f((ushort)vv[3]);
    a4 += bf2f((ushort)vv[4]); a5 += bf2f((ushort)vv[5]);
    a6 += bf2f((ushort)vv[6]); a7 += bf2f((ushort)vv[7]);
  }
  a0 += __shfl_xor(a0, 8); a0 += __shfl_xor(a0, 16); a0 += __shfl_xor(a0, 32);
  a1 += __shfl_xor(a1, 8); a1 += __shfl_xor(a1, 16); a1 += __shfl_xor(a1, 32);
  a2 += __shfl_xor(a2, 8); a2 += __shfl_xor(a2, 16); a2 += __shfl_xor(a2, 32);
  a3 += __shfl_xor(a3, 8); a3 += __shfl_xor(a3, 16); a3 += __shfl_xor(a3, 32);
  a4 += __shfl_xor(a4, 8); a4 += __shfl_xor(a4, 16); a4 += __shfl_xor(a4, 32);
  a5 += __shfl_xor(a5, 8); a5 += __shfl_xor(a5, 16); a5 += __shfl_xor(a5, 32);
  a6 += __shfl_xor(a6, 8); a6 += __shfl_xor(a6, 16); a6 += __shfl_xor(a6, 32);
  a7 += __shfl_xor(a7, 8); a7 += __shfl_xor(a7, 16); a7 += __shfl_xor(a7, 32);
  if (g == 0) {
    float inv = 1.f / (float)(len > 0 ? len : 1);
    s8v o;
    o[0] = (short)f2bf(a0 * inv); o[1] = (short)f2bf(a1 * inv);
    o[2] = (short)f2bf(a2 * inv); o[3] = (short)f2bf(a3 * inv);
    o[4] = (short)f2bf(a4 * inv); o[5] = (short)f2bf(a5 * inv);
    o[6] = (short)f2bf(a6 * inv); o[7] = (short)f2bf(a7 * inv);
    *(s8v*)(agg + (size_t)node * 64 + c8) = o;
  }
}

// ---------------- layer transform via MFMA: 32 nodes/wave ----------------

__global__ __launch_bounds__(256) void k_xform_mfma(
    const ushort* __restrict__ fb, const ushort* __restrict__ ab,
    const ushort* __restrict__ wtS, const ushort* __restrict__ wtN,
    const float* __restrict__ bias, ushort* __restrict__ outb, int N)
{
  int lane = threadIdx.x & 63;
  int wid  = threadIdx.x >> 6;
  int wbase = blockIdx.x * 128 + wid * 32;
  if (wbase >= N) return;
  int lrow = lane & 15;
  int lkg  = lane >> 4;

  // B-fragments: L1-resident, loaded once per wave
  s8v bS[4][2], bN[4][2];
  #pragma unroll
  for (int nt = 0; nt < 4; ++nt) {
    #pragma unroll
    for (int ks = 0; ks < 2; ++ks) {
      int o = (nt * 16 + lrow) * 64 + ks * 32 + lkg * 8;
      bS[nt][ks] = *(const s8v*)(wtS + o);
      bN[nt][ks] = *(const s8v*)(wtN + o);
    }
  }

  f4v acc[2][4];
  #pragma unroll
  for (int a = 0; a < 2; ++a)
    #pragma unroll
    for (int b = 0; b < 4; ++b)
      acc[a][b] = (f4v){0.f, 0.f, 0.f, 0.f};

  #pragma unroll
  for (int pt = 0; pt < 2; ++pt) {
    int node = wbase + pt * 16 + lrow;
    int nc = (node < N) ? node : (N - 1);
    const ushort* fr = fb + (size_t)nc * 64 + lkg * 8;
    const ushort* ar = ab + (size_t)nc * 64 + lkg * 8;
    s8v f0 = *(const s8v*)(fr);
    s8v f1 = *(const s8v*)(fr + 32);
    s8v g0 = *(const s8v*)(ar);
    s8v g1 = *(const s8v*)(ar + 32);
    #pragma unroll
    for (int nt = 0; nt < 4; ++nt) {
      acc[pt][nt] = __builtin_amdgcn_mfma_f32_16x16x32_bf16(f0, bS[nt][0], acc[pt][nt], 0, 0, 0);
      acc[pt][nt] = __builtin_amdgcn_mfma_f32_16x16x32_bf16(f1, bS[nt][1], acc[pt][nt], 0, 0, 0);
      acc[pt][nt] = __builtin_amdgcn_mfma_f32_16x16x32_bf16(g0, bN[nt][0], acc[pt][nt], 0, 0, 0);
      acc[pt][nt] = __builtin_amdgcn_mfma_f32_16x16x32_bf16(g1, bN[nt][1], acc[pt][nt], 0, 0, 0);
    }
  }

  float bv[4];
  #pragma unroll
  for (int nt = 0; nt < 4; ++nt) bv[nt] = bias[nt * 16 + lrow];

  #pragma unroll
  for (int pt = 0; pt < 2; ++pt) {
    #pragma unroll
    for (int r = 0; r < 4; ++r) {
      int node = wbase + pt * 16 + lkg * 4 + r;
      if (node < N) {
        ushort* orow = outb + (size_t)node * 64;
        #pragma unroll
        for (int nt = 0; nt < 4; ++nt) {
          float z = fmaxf(acc[pt][nt][r] + bv[nt], 0.f);
          orow[nt * 16 + lrow] = f2bf(z);
        }
      }
    }
  }
}

// ---------------- head via MFMA: persistent blocks, W staged ONCE per block ----------------

__global__ __launch_bounds__(256) void k_head_mfma(
    const ushort* __restrict__ hb, const int* __restrict__ x1, const int* __restrict__ x2,
    const ushort* __restrict__ w1t, const float* __restrict__ bl1,
    const float* __restrict__ W2, const float* __restrict__ bl2,
    float* __restrict__ out, int P)
{
  __shared__ __align__(16) ushort sW[64 * 200];
  __shared__ float sW2[128];
  __shared__ float sb1[64];
  __shared__ float sb2[2];
  {
    const float4* srcv = (const float4*)w1t;   // 12800 ushort = 1600 float4
    float4* dstv = (float4*)sW;
    for (int i = threadIdx.x; i < 1600; i += 256) dstv[i] = srcv[i];
    if (threadIdx.x < 128) sW2[threadIdx.x] = W2[threadIdx.x];
    if (threadIdx.x < 64)  sb1[threadIdx.x] = bl1[threadIdx.x];
    if (threadIdx.x < 2)   sb2[threadIdx.x] = bl2[threadIdx.x];
  }
  __syncthreads();

  int lane = threadIdx.x & 63;
  int wid  = threadIdx.x >> 6;
  int lrow = lane & 15;
  int lkg  = lane >> 4;

  float b1v[4], w20v[4], w21v[4];
  #pragma unroll
  for (int nt = 0; nt < 4; ++nt) {
    int n = nt * 16 + lrow;
    b1v[nt] = sb1[n];
    w20v[nt] = sW2[2 * n + 0];
    w21v[nt] = sW2[2 * n + 1];
  }
  float bb0 = sb2[0], bb1 = sb2[1];

  int nTiles = (P + 127) / 128;
  for (int tile = blockIdx.x; tile < nTiles; tile += gridDim.x) {
    int wbase = tile * 128 + wid * 32;   // 32 pairs per wave
    if (wbase >= P) continue;

    // pair gathers (clamped)
    int pa = wbase + lrow;
    int pb = wbase + 16 + lrow;
    int pca = (pa < P) ? pa : (P - 1);
    int pcb = (pb < P) ? pb : (P - 1);
    int i1a = x1[pca], i2a = x2[pca];
    int i1b = x1[pcb], i2b = x2[pcb];
    const ushort* r1a = hb + (size_t)i1a * 64 + lkg * 8;
    const ushort* r2a = hb + (size_t)i2a * 64 + lkg * 8;
    const ushort* r1b = hb + (size_t)i1b * 64 + lkg * 8;
    const ushort* r2b = hb + (size_t)i2b * 64 + lkg * 8;
    s8v a1a0 = *(const s8v*)(r1a);
    s8v a1a1 = *(const s8v*)(r1a + 32);
    s8v a2a0 = *(const s8v*)(r2a);
    s8v a2a1 = *(const s8v*)(r2a + 32);
    s8v a1b0 = *(const s8v*)(r1b);
    s8v a1b1 = *(const s8v*)(r1b + 32);
    s8v a2b0 = *(const s8v*)(r2b);
    s8v a2b1 = *(const s8v*)(r2b + 32);

    s8v da0 = absdiff_bf(a1a0, a2a0);
    s8v da1 = absdiff_bf(a1a1, a2a1);
    s8v db0 = absdiff_bf(a1b0, a2b0);
    s8v db1 = absdiff_bf(a1b1, a2b1);

    f4v acc[2][4];
    #pragma unroll
    for (int a = 0; a < 2; ++a)
      #pragma unroll
      for (int b = 0; b < 4; ++b)
        acc[a][b] = (f4v){0.f, 0.f, 0.f, 0.f};

    #pragma unroll
    for (int nt = 0; nt < 4; ++nt) {
      const ushort* bw = &sW[(nt * 16 + lrow) * 200 + lkg * 8];
      s8v b1_0 = *(const s8v*)(bw + 0);
      s8v b2_0 = *(const s8v*)(bw + 64);
      s8v b3_0 = *(const s8v*)(bw + 128);
      acc[0][nt] = __builtin_amdgcn_mfma_f32_16x16x32_bf16(a1a0, b1_0, acc[0][nt], 0, 0, 0);
      acc[0][nt] = __builtin_amdgcn_mfma_f32_16x16x32_bf16(a2a0, b2_0, acc[0][nt], 0, 0, 0);
      acc[0][nt] = __builtin_amdgcn_mfma_f32_16x16x32_bf16(da0,  b3_0, acc[0][nt], 0, 0, 0);
      acc[1][nt] = __builtin_amdgcn_mfma_f32_16x16x32_bf16(a1b0, b1_0, acc[1][nt], 0, 0, 0);
      acc[1][nt] = __builtin_amdgcn_mfma_f32_16x16x32_bf16(a2b0, b2_0, acc[1][nt], 0, 0, 0);
      acc[1][nt] = __builtin_amdgcn_mfma_f32_16x16x32_bf16(db0,  b3_0, acc[1][nt], 0, 0, 0);
      s8v b1_1 = *(const s8v*)(bw + 32);
      s8v b2_1 = *(const s8v*)(bw + 96);
      s8v b3_1 = *(const s8v*)(bw + 160);
      acc[0][nt] = __builtin_amdgcn_mfma_f32_16x16x32_bf16(a1a1, b1_1, acc[0][nt], 0, 0, 0);
      acc[0][nt] = __builtin_amdgcn_mfma_f32_16x16x32_bf16(a2a1, b2_1, acc[0][nt], 0, 0, 0);
      acc[0][nt] = __builtin_amdgcn_mfma_f32_16x16x32_bf16(da1,  b3_1, acc[0][nt], 0, 0, 0);
      acc[1][nt] = __builtin_amdgcn_mfma_f32_16x16x32_bf16(a1b1, b1_1, acc[1][nt], 0, 0, 0);
      acc[1][nt] = __builtin_amdgcn_mfma_f32_16x16x32_bf16(a2b1, b2_1, acc[1][nt], 0, 0, 0);
      acc[1][nt] = __builtin_amdgcn_mfma_f32_16x16x32_bf16(db1,  b3_1, acc[1][nt], 0, 0, 0);
    }

    #pragma unroll
    for (int pt = 0; pt < 2; ++pt) {
      #pragma unroll
      for (int r = 0; r < 4; ++r) {
        float p0 = 0.f, p1 = 0.f;
        #pragma unroll
        for (int nt = 0; nt < 4; ++nt) {
          float z = fmaxf(acc[pt][nt][r] + b1v[nt], 0.f);
          p0 += z * w20v[nt];
          p1 += z * w21v[nt];
        }
        p0 += __shfl_xor(p0, 1); p1 += __shfl_xor(p1, 1);
        p0 += __shfl_xor(p0, 2); p1 += __shfl_xor(p1, 2);
        p0 += __shfl_xor(p0, 4); p1 += __shfl_xor(p1, 4);
        p0 += __shfl_xor(p0, 8); p1 += __shfl_xor(p1, 8);
        int pair = wbase + pt * 16 + lkg * 4 + r;
        if (lrow == 0 && pair < P) {
          float2 o = make_float2(p0 + bb0, p1 + bb1);
          *(float2*)(out + 2 * (size_t)pair) = o;
        }
      }
    }
  }
}

// ---------------- launch ----------------

extern "C" void kernel_launch(void* const* d_in, const int* in_sizes, int n_in,
                              void* d_out, int out_size, void* d_ws, size_t ws_size,
                              hipStream_t stream)
{
  (void)n_in; (void)out_size; (void)ws_size;
  const float* h   = (const float*)d_in[0];
  const int*   src = (const int*)d_in[1];
  const int*   dst = (const int*)d_in[2];
  const int*   x1  = (const int*)d_in[3];
  const int*   x2  = (const int*)d_in[4];
  const float* Ws0 = (const float*)d_in[5];
  const float* Wn0 = (const float*)d_in[6];
  const float* b0  = (const float*)d_in[7];
  const float* Ws1 = (const float*)d_in[8];
  const float* Wn1 = (const float*)d_in[9];
  const float* b1  = (const float*)d_in[10];
  const float* W1  = (const float*)d_in[11];
  const float* bl1 = (const float*)d_in[12];
  const float* W2  = (const float*)d_in[13];
  const float* bl2 = (const float*)d_in[14];

  const int N = in_sizes[0] / 64;
  const int E = in_sizes[1];
  const int P = in_sizes[3];
  const int B = (N + NPB - 1) >> BSH;
  float* out = (float*)d_out;

  const int NCH = (E + CHUNK - 1) / CHUNK;
  const int n8  = N * 64 / 8;

  char* ws = (char*)d_ws;
  size_t off = 0;
  auto carve = [&](size_t bytes) {
    char* p = ws + off;
    off = (off + bytes + 255) & ~(size_t)255;
    return p;
  };
  int*    row_ptr      = (int*)carve((size_t)(N + 1) * 4);
  int*    chunkHist    = (int*)carve((size_t)NCH * MAXB * 4);
  int*    bucketCnt    = (int*)carve(MAXB * 4);
  int*    bucketBase   = (int*)carve((MAXB + 1) * 4);
  int*    bucketCursor = (int*)carve(MAXB * 4);
  int*    csr_src  = (int*)carve((size_t)E * 4);
  ushort* h_bf     = (ushort*)carve((size_t)N * 64 * 2);
  ushort* m1       = (ushort*)carve((size_t)N * 64 * 2);
  ushort* m2       = (ushort*)carve((size_t)N * 64 * 2);
  int2*   stag     = (int2*)carve((size_t)E * 8);
  ushort* aggb     = (ushort*)carve((size_t)N * 64 * 2);
  ushort* w1t      = (ushort*)carve(64 * 200 * 2);
  ushort* wtS0     = (ushort*)carve(4096 * 2);
  ushort* wtN0     = (ushort*)carve(4096 * 2);
  ushort* wtS1     = (ushort*)carve(4096 * 2);
  ushort* wtN1     = (ushort*)carve(4096 * 2);

  k_prep<<<(n8 + 255) / 256, 256, 0, stream>>>(h, W1, Ws0, Wn0, Ws1, Wn1, dst,
                                               h_bf, w1t, wtS0, wtN0, wtS1, wtN1,
                                               chunkHist, n8, E, NCH);
  k_hsum<<<MAXB, 256, 0, stream>>>(chunkHist, bucketCnt, NCH);
  k_bscan<<<1, MAXB, 0, stream>>>(bucketCnt, bucketBase, bucketCursor, row_ptr, B, N, E);
  k_part <<<NCH, 256, 0, stream>>>(src, dst, bucketCursor, stag, E);
  k_csr_bucket<<<B, NPB, 0, stream>>>(stag, bucketBase, row_ptr, csr_src, N);

  const int nbW = (N + 3) / 4;
  const int nbX = (N + 127) / 128;   // 128 nodes per block (32/wave)

  k_agg_bf<<<nbW, 256, 0, stream>>>(h_bf, row_ptr, csr_src, aggb, N);
  k_xform_mfma<<<nbX, 256, 0, stream>>>(h_bf, aggb, wtS0, wtN0, b0, m1, N);
  k_agg_bf<<<nbW, 256, 0, stream>>>(m1, row_ptr, csr_src, aggb, N);
  k_xform_mfma<<<nbX, 256, 0, stream>>>(m1, aggb, wtS1, wtN1, b1, m2, N);

  const int nTiles = (P + 127) / 128;
  const int nbP = (nTiles < HEAD_BLOCKS) ? nTiles : HEAD_BLOCKS;
  k_head_mfma<<<nbP, 256, 0, stream>>>(m2, x1, x2, w1t, bl1, W2, bl2, out, P);
}

// Round 14
// 181.026 us; speedup vs baseline: 1.3117x; 1.0390x over previous
//
#include <hip/hip_runtime.h>
#include <hip/hip_bf16.h>

using s8v = __attribute__((ext_vector_type(8))) short;   // 8 bf16 (4 VGPRs)
using f4v = __attribute__((ext_vector_type(4))) float;   // MFMA accumulator

__device__ __forceinline__ float bf2f(ushort v) { return __uint_as_float(((unsigned)v) << 16); }
__device__ __forceinline__ ushort f2bf(float x) {
  unsigned u = __float_as_uint(x);
  return (ushort)((u + 0x7fffu + ((u >> 16) & 1u)) >> 16);   // RNE, matches numpy
}

// |x - y| for 8 bf16 elems, result bf16, via v_cvt_pk_bf16_f32 (RNE)
__device__ __forceinline__ s8v absdiff_bf(s8v x, s8v y) {
  s8v d;
  #pragma unroll
  for (int q = 0; q < 4; ++q) {
    float f0 = fabsf(bf2f((ushort)x[2*q+0]) - bf2f((ushort)y[2*q+0]));
    float f1 = fabsf(bf2f((ushort)x[2*q+1]) - bf2f((ushort)y[2*q+1]));
    unsigned w;
    asm("v_cvt_pk_bf16_f32 %0, %1, %2" : "=v"(w) : "v"(f0), "v"(f1));
    d[2*q+0] = (short)(w & 0xffffu);
    d[2*q+1] = (short)(w >> 16);
  }
  return d;
}

#define BSH 9                    // 512 nodes per bucket
#define NPB 512
#define MAXB 256                 // covers N <= 131072
#define CHUNK 4096
#define HEAD_BLOCKS 1024         // persistent head grid (4 blocks/CU)

// ---------------- fused prep: cast h->bf16 + weight preps + per-chunk histogram ----------------

__global__ __launch_bounds__(256) void k_prep(
    const float* __restrict__ h, const float* __restrict__ W1,
    const float* __restrict__ Ws0, const float* __restrict__ Wn0,
    const float* __restrict__ Ws1, const float* __restrict__ Wn1,
    const int* __restrict__ dst,
    ushort* __restrict__ h_bf, ushort* __restrict__ w1t,
    ushort* __restrict__ tS0, ushort* __restrict__ tN0,
    ushort* __restrict__ tS1, ushort* __restrict__ tN1,
    int* __restrict__ chunkHist, int n8, int E, int nch)
{
  __shared__ int hh[MAXB];
  int t = threadIdx.x;
  int i = blockIdx.x * 256 + t;

  if (i < 4096) {            // layer weights -> bf16 transposed [j][k]
    int j = i >> 6, k = i & 63;
    int o = k * 64 + j;
    tS0[i] = f2bf(Ws0[o]);
    tN0[i] = f2bf(Wn0[o]);
    tS1[i] = f2bf(Ws1[o]);
    tN1[i] = f2bf(Wn1[o]);
  }
  if (i < 64 * 200) {        // W1 -> transposed bf16 [n][200], zero-padded
    int n = i / 200, k = i % 200;
    float v = (k < 192) ? W1[k * 64 + n] : 0.f;
    w1t[i] = f2bf(v);
  }
  if (i < n8) {              // h -> bf16, 8 elems/thread
    const float4* in4 = (const float4*)h;
    float4 va = in4[2 * i], vb = in4[2 * i + 1];
    s8v w;
    w[0] = (short)f2bf(va.x); w[1] = (short)f2bf(va.y);
    w[2] = (short)f2bf(va.z); w[3] = (short)f2bf(va.w);
    w[4] = (short)f2bf(vb.x); w[5] = (short)f2bf(vb.y);
    w[6] = (short)f2bf(vb.z); w[7] = (short)f2bf(vb.w);
    ((s8v*)h_bf)[i] = w;
  }
  if (blockIdx.x < (unsigned)nch) {   // bucket histogram for this chunk
    hh[t] = 0;
    __syncthreads();
    int base = blockIdx.x * CHUNK;
    #pragma unroll
    for (int k = 0; k < CHUNK / 256; ++k) {
      int e = base + k * 256 + t;
      if (e < E) atomicAdd(&hh[dst[e] >> BSH], 1);
    }
    __syncthreads();
    chunkHist[blockIdx.x * MAXB + t] = hh[t];
  }
}

// ---------------- phase 1b: parallel reduction of chunk histograms ----------------

__global__ __launch_bounds__(256) void k_hsum(const int* __restrict__ chunkHist,
                                              int* __restrict__ bucketCnt, int nch) {
  __shared__ int sh[256];
  int b = blockIdx.x;
  int t = threadIdx.x;
  int v = 0;
  for (int c = t; c < nch; c += 256) v += chunkHist[c * MAXB + b];
  sh[t] = v;
  __syncthreads();
  for (int o = 128; o > 0; o >>= 1) {
    if (t < o) sh[t] += sh[t + o];
    __syncthreads();
  }
  if (t == 0) bucketCnt[b] = sh[0];
}

// ---------------- phase 2: scan buckets -> base & cursor ----------------

__global__ __launch_bounds__(256) void k_bscan(const int* __restrict__ bucketCnt,
                                               int* __restrict__ bucketBase,
                                               int* __restrict__ bucketCursor,
                                               int* __restrict__ row_ptr,
                                               int B, int N, int E) {
  __shared__ int sh[MAXB];
  int t = threadIdx.x;
  int v = (t < B) ? bucketCnt[t] : 0;
  sh[t] = v;
  __syncthreads();
  for (int off = 1; off < MAXB; off <<= 1) {
    int y = (t >= off) ? sh[t - off] : 0;
    __syncthreads();
    sh[t] += y;
    __syncthreads();
  }
  int excl = sh[t] - v;
  if (t < B) { bucketBase[t] = excl; bucketCursor[t] = excl; }
  if (t == 0) { bucketBase[B] = E; row_ptr[N] = E; }
}

// ---------------- phase 3: partition edges into bucket-grouped staging ----------------

__global__ __launch_bounds__(256) void k_part(
    const int* __restrict__ src, const int* __restrict__ dst,
    int* __restrict__ bucketCursor, int2* __restrict__ stag, int E)
{
  __shared__ int hh[MAXB];     // local hist
  __shared__ int sc[MAXB];     // local exclusive scan
  __shared__ int cur[MAXB];    // placement cursor
  __shared__ int gb[MAXB];     // global base for this block's run
  __shared__ int2 pairs[CHUNK];

  int t = threadIdx.x;
  int base = blockIdx.x * CHUNK;
  int M = E - base; if (M > CHUNK) M = CHUNK;

  int es[CHUNK / 256], ed[CHUNK / 256];
  #pragma unroll
  for (int k = 0; k < CHUNK / 256; ++k) {
    int e = base + k * 256 + t;
    if (e < E) { es[k] = src[e]; ed[k] = dst[e]; } else { ed[k] = -1; }
  }

  hh[t] = 0;
  __syncthreads();
  #pragma unroll
  for (int k = 0; k < CHUNK / 256; ++k)
    if (ed[k] >= 0) atomicAdd(&hh[ed[k] >> BSH], 1);
  __syncthreads();

  // exclusive scan of hh[0..256) with 256 threads
  int v = hh[t];
  sc[t] = v;
  __syncthreads();
  for (int off = 1; off < MAXB; off <<= 1) {
    int y = (t >= off) ? sc[t - off] : 0;
    __syncthreads();
    sc[t] += y;
    __syncthreads();
  }
  int excl = sc[t] - v;
  sc[t] = excl;
  cur[t] = excl;
  if (v) gb[t] = atomicAdd(&bucketCursor[t], v);
  __syncthreads();

  // place pairs bucket-major into LDS
  #pragma unroll
  for (int k = 0; k < CHUNK / 256; ++k)
    if (ed[k] >= 0) {
      int b = ed[k] >> BSH;
      int pos = atomicAdd(&cur[b], 1);
      pairs[pos] = make_int2(es[k], ed[k]);
    }
  __syncthreads();

  // write out: slot s of bucket b goes to stag[gb[b] + s - sc[b]]
  for (int s = t; s < M; s += 256) {
    int2 pr = pairs[s];
    int b = pr.y >> BSH;
    stag[gb[b] + s - sc[b]] = pr;
  }
}

// ---------------- phase 4: per-bucket CSR finalize ----------------

__global__ __launch_bounds__(512) void k_csr_bucket(
    const int2* __restrict__ stag, const int* __restrict__ bucketBase,
    int* __restrict__ row_ptr, int* __restrict__ csr_src, int N)
{
  __shared__ int dh[NPB], db[NPB], dc[NPB];
  int t = threadIdx.x;
  int b = blockIdx.x;
  int n0 = b << BSH;
  int nn = N - n0; if (nn > NPB) nn = NPB;
  int estart = bucketBase[b], eend = bucketBase[b + 1];

  dh[t] = 0;
  __syncthreads();
  for (int e = estart + t; e < eend; e += 512)
    atomicAdd(&dh[stag[e].y - n0], 1);
  __syncthreads();
  int v = dh[t];
  db[t] = v;
  __syncthreads();
  for (int off = 1; off < NPB; off <<= 1) {
    int y = (t >= off) ? db[t - off] : 0;
    __syncthreads();
    db[t] += y;
    __syncthreads();
  }
  int excl = db[t] - v;
  if (t < nn) row_ptr[n0 + t] = estart + excl;
  dc[t] = excl;
  __syncthreads();
  for (int e = estart + t; e < eend; e += 512) {
    int2 pr = stag[e];
    int d = pr.y - n0;
    int pos = estart + atomicAdd(&dc[d], 1);
    csr_src[pos] = pr.x;
  }
}

// ---------------- aggregation: wave-per-node, 2x unrolled ----------------
// Epilogue: LDS transpose-reduce (2x ds_write_b128 + 8 stride-64 reads,
// 2-way bank aliasing = free) replaces 24-bpermute butterfly; all 64 lanes
// pack + one coalesced 128B store.

__global__ __launch_bounds__(256) void k_agg_bf(
    const ushort* __restrict__ fb, const int* __restrict__ rp,
    const int* __restrict__ csrc, ushort* __restrict__ agg, int N)
{
  __shared__ float red[4][512];
  int lane = threadIdx.x & 63;
  int wid  = threadIdx.x >> 6;
  int node = (blockIdx.x * 256 + threadIdx.x) >> 6;
  if (node >= N) return;
  int g  = lane >> 3;
  int c8 = (lane & 7) * 8;
  int e0 = rp[node], e1 = rp[node + 1];
  int len = e1 - e0;
  float a0=0.f,a1=0.f,a2=0.f,a3=0.f,a4=0.f,a5=0.f,a6=0.f,a7=0.f;
  int nfull = len >> 3;
  int it = 0;
  int e = e0;
  for (; it + 2 <= nfull; it += 2, e += 16) {
    int sA = csrc[e + g];
    int sB = csrc[e + 8 + g];
    s8v va = *(const s8v*)(fb + (size_t)sA * 64 + c8);
    s8v vb = *(const s8v*)(fb + (size_t)sB * 64 + c8);
    a0 += bf2f((ushort)va[0]); a1 += bf2f((ushort)va[1]);
    a2 += bf2f((ushort)va[2]); a3 += bf2f((ushort)va[3]);
    a4 += bf2f((ushort)va[4]); a5 += bf2f((ushort)va[5]);
    a6 += bf2f((ushort)va[6]); a7 += bf2f((ushort)va[7]);
    a0 += bf2f((ushort)vb[0]); a1 += bf2f((ushort)vb[1]);
    a2 += bf2f((ushort)vb[2]); a3 += bf2f((ushort)vb[3]);
    a4 += bf2f((ushort)vb[4]); a5 += bf2f((ushort)vb[5]);
    a6 += bf2f((ushort)vb[6]); a7 += bf2f((ushort)vb[7]);
  }
  if (it < nfull) {
    int s = csrc[e + g];
    s8v vv = *(const s8v*)(fb + (size_t)s * 64 + c8);
    a0 += bf2f((ushort)vv[0]); a1 += bf2f((ushort)vv[1]);
    a2 += bf2f((ushort)vv[2]); a3 += bf2f((ushort)vv[3]);
    a4 += bf2f((ushort)vv[4]); a5 += bf2f((ushort)vv[5]);
    a6 += bf2f((ushort)vv[6]); a7 += bf2f((ushort)vv[7]);
    e += 8;
  }
  if (e + g < e1) {
    int s = csrc[e + g];
    s8v vv = *(const s8v*)(fb + (size_t)s * 64 + c8);
    a0 += bf2f((ushort)vv[0]); a1 += bf2f((ushort)vv[1]);
    a2 += bf2f((ushort)vv[2]); a3 += bf2f((ushort)vv[3]);
    a4 += bf2f((ushort)vv[4]); a5 += bf2f((ushort)vv[5]);
    a6 += bf2f((ushort)vv[6]); a7 += bf2f((ushort)vv[7]);
  }

  // LDS transpose-reduce: lane (g,c) writes partials for columns c*8+j at
  // red[wid][g*64 + c*8 + j]; lane `col` then sums over g at stride 64.
  float* rw = &red[wid][0];
  float4 w0 = make_float4(a0, a1, a2, a3);
  float4 w1 = make_float4(a4, a5, a6, a7);
  *(float4*)(rw + lane * 8 + 0) = w0;
  *(float4*)(rw + lane * 8 + 4) = w1;
  float s = 0.f;
  #pragma unroll
  for (int g2 = 0; g2 < 8; ++g2) s += rw[g2 * 64 + lane];
  float inv = 1.f / (float)(len > 0 ? len : 1);
  agg[(size_t)node * 64 + lane] = f2bf(s * inv);
}

// ---------------- layer transform via MFMA: 32 nodes/wave ----------------

__global__ __launch_bounds__(256) void k_xform_mfma(
    const ushort* __restrict__ fb, const ushort* __restrict__ ab,
    const ushort* __restrict__ wtS, const ushort* __restrict__ wtN,
    const float* __restrict__ bias, ushort* __restrict__ outb, int N)
{
  int lane = threadIdx.x & 63;
  int wid  = threadIdx.x >> 6;
  int wbase = blockIdx.x * 128 + wid * 32;
  if (wbase >= N) return;
  int lrow = lane & 15;
  int lkg  = lane >> 4;

  // B-fragments: L1-resident, loaded once per wave
  s8v bS[4][2], bN[4][2];
  #pragma unroll
  for (int nt = 0; nt < 4; ++nt) {
    #pragma unroll
    for (int ks = 0; ks < 2; ++ks) {
      int o = (nt * 16 + lrow) * 64 + ks * 32 + lkg * 8;
      bS[nt][ks] = *(const s8v*)(wtS + o);
      bN[nt][ks] = *(const s8v*)(wtN + o);
    }
  }

  f4v acc[2][4];
  #pragma unroll
  for (int a = 0; a < 2; ++a)
    #pragma unroll
    for (int b = 0; b < 4; ++b)
      acc[a][b] = (f4v){0.f, 0.f, 0.f, 0.f};

  #pragma unroll
  for (int pt = 0; pt < 2; ++pt) {
    int node = wbase + pt * 16 + lrow;
    int nc = (node < N) ? node : (N - 1);
    const ushort* fr = fb + (size_t)nc * 64 + lkg * 8;
    const ushort* ar = ab + (size_t)nc * 64 + lkg * 8;
    s8v f0 = *(const s8v*)(fr);
    s8v f1 = *(const s8v*)(fr + 32);
    s8v g0 = *(const s8v*)(ar);
    s8v g1 = *(const s8v*)(ar + 32);
    #pragma unroll
    for (int nt = 0; nt < 4; ++nt) {
      acc[pt][nt] = __builtin_amdgcn_mfma_f32_16x16x32_bf16(f0, bS[nt][0], acc[pt][nt], 0, 0, 0);
      acc[pt][nt] = __builtin_amdgcn_mfma_f32_16x16x32_bf16(f1, bS[nt][1], acc[pt][nt], 0, 0, 0);
      acc[pt][nt] = __builtin_amdgcn_mfma_f32_16x16x32_bf16(g0, bN[nt][0], acc[pt][nt], 0, 0, 0);
      acc[pt][nt] = __builtin_amdgcn_mfma_f32_16x16x32_bf16(g1, bN[nt][1], acc[pt][nt], 0, 0, 0);
    }
  }

  float bv[4];
  #pragma unroll
  for (int nt = 0; nt < 4; ++nt) bv[nt] = bias[nt * 16 + lrow];

  #pragma unroll
  for (int pt = 0; pt < 2; ++pt) {
    #pragma unroll
    for (int r = 0; r < 4; ++r) {
      int node = wbase + pt * 16 + lkg * 4 + r;
      if (node < N) {
        ushort* orow = outb + (size_t)node * 64;
        #pragma unroll
        for (int nt = 0; nt < 4; ++nt) {
          float z = fmaxf(acc[pt][nt][r] + bv[nt], 0.f);
          orow[nt * 16 + lrow] = f2bf(z);
        }
      }
    }
  }
}

// ---------------- head via MFMA: persistent blocks, W staged ONCE per block ----------------

__global__ __launch_bounds__(256) void k_head_mfma(
    const ushort* __restrict__ hb, const int* __restrict__ x1, const int* __restrict__ x2,
    const ushort* __restrict__ w1t, const float* __restrict__ bl1,
    const float* __restrict__ W2, const float* __restrict__ bl2,
    float* __restrict__ out, int P)
{
  __shared__ __align__(16) ushort sW[64 * 200];
  __shared__ float sW2[128];
  __shared__ float sb1[64];
  __shared__ float sb2[2];
  {
    const float4* srcv = (const float4*)w1t;   // 12800 ushort = 1600 float4
    float4* dstv = (float4*)sW;
    for (int i = threadIdx.x; i < 1600; i += 256) dstv[i] = srcv[i];
    if (threadIdx.x < 128) sW2[threadIdx.x] = W2[threadIdx.x];
    if (threadIdx.x < 64)  sb1[threadIdx.x] = bl1[threadIdx.x];
    if (threadIdx.x < 2)   sb2[threadIdx.x] = bl2[threadIdx.x];
  }
  __syncthreads();

  int lane = threadIdx.x & 63;
  int wid  = threadIdx.x >> 6;
  int lrow = lane & 15;
  int lkg  = lane >> 4;

  float b1v[4], w20v[4], w21v[4];
  #pragma unroll
  for (int nt = 0; nt < 4; ++nt) {
    int n = nt * 16 + lrow;
    b1v[nt] = sb1[n];
    w20v[nt] = sW2[2 * n + 0];
    w21v[nt] = sW2[2 * n + 1];
  }
  float bb0 = sb2[0], bb1 = sb2[1];

  int nTiles = (P + 127) / 128;
  for (int tile = blockIdx.x; tile < nTiles; tile += gridDim.x) {
    int wbase = tile * 128 + wid * 32;   // 32 pairs per wave
    if (wbase >= P) continue;

    // pair gathers (clamped)
    int pa = wbase + lrow;
    int pb = wbase + 16 + lrow;
    int pca = (pa < P) ? pa : (P - 1);
    int pcb = (pb < P) ? pb : (P - 1);
    int i1a = x1[pca], i2a = x2[pca];
    int i1b = x1[pcb], i2b = x2[pcb];
    const ushort* r1a = hb + (size_t)i1a * 64 + lkg * 8;
    const ushort* r2a = hb + (size_t)i2a * 64 + lkg * 8;
    const ushort* r1b = hb + (size_t)i1b * 64 + lkg * 8;
    const ushort* r2b = hb + (size_t)i2b * 64 + lkg * 8;
    s8v a1a0 = *(const s8v*)(r1a);
    s8v a1a1 = *(const s8v*)(r1a + 32);
    s8v a2a0 = *(const s8v*)(r2a);
    s8v a2a1 = *(const s8v*)(r2a + 32);
    s8v a1b0 = *(const s8v*)(r1b);
    s8v a1b1 = *(const s8v*)(r1b + 32);
    s8v a2b0 = *(const s8v*)(r2b);
    s8v a2b1 = *(const s8v*)(r2b + 32);

    s8v da0 = absdiff_bf(a1a0, a2a0);
    s8v da1 = absdiff_bf(a1a1, a2a1);
    s8v db0 = absdiff_bf(a1b0, a2b0);
    s8v db1 = absdiff_bf(a1b1, a2b1);

    f4v acc[2][4];
    #pragma unroll
    for (int a = 0; a < 2; ++a)
      #pragma unroll
      for (int b = 0; b < 4; ++b)
        acc[a][b] = (f4v){0.f, 0.f, 0.f, 0.f};

    #pragma unroll
    for (int nt = 0; nt < 4; ++nt) {
      const ushort* bw = &sW[(nt * 16 + lrow) * 200 + lkg * 8];
      s8v b1_0 = *(const s8v*)(bw + 0);
      s8v b2_0 = *(const s8v*)(bw + 64);
      s8v b3_0 = *(const s8v*)(bw + 128);
      acc[0][nt] = __builtin_amdgcn_mfma_f32_16x16x32_bf16(a1a0, b1_0, acc[0][nt], 0, 0, 0);
      acc[0][nt] = __builtin_amdgcn_mfma_f32_16x16x32_bf16(a2a0, b2_0, acc[0][nt], 0, 0, 0);
      acc[0][nt] = __builtin_amdgcn_mfma_f32_16x16x32_bf16(da0,  b3_0, acc[0][nt], 0, 0, 0);
      acc[1][nt] = __builtin_amdgcn_mfma_f32_16x16x32_bf16(a1b0, b1_0, acc[1][nt], 0, 0, 0);
      acc[1][nt] = __builtin_amdgcn_mfma_f32_16x16x32_bf16(a2b0, b2_0, acc[1][nt], 0, 0, 0);
      acc[1][nt] = __builtin_amdgcn_mfma_f32_16x16x32_bf16(db0,  b3_0, acc[1][nt], 0, 0, 0);
      s8v b1_1 = *(const s8v*)(bw + 32);
      s8v b2_1 = *(const s8v*)(bw + 96);
      s8v b3_1 = *(const s8v*)(bw + 160);
      acc[0][nt] = __builtin_amdgcn_mfma_f32_16x16x32_bf16(a1a1, b1_1, acc[0][nt], 0, 0, 0);
      acc[0][nt] = __builtin_amdgcn_mfma_f32_16x16x32_bf16(a2a1, b2_1, acc[0][nt], 0, 0, 0);
      acc[0][nt] = __builtin_amdgcn_mfma_f32_16x16x32_bf16(da1,  b3_1, acc[0][nt], 0, 0, 0);
      acc[1][nt] = __builtin_amdgcn_mfma_f32_16x16x32_bf16(a1b1, b1_1, acc[1][nt], 0, 0, 0);
      acc[1][nt] = __builtin_amdgcn_mfma_f32_16x16x32_bf16(a2b1, b2_1, acc[1][nt], 0, 0, 0);
      acc[1][nt] = __builtin_amdgcn_mfma_f32_16x16x32_bf16(db1,  b3_1, acc[1][nt], 0, 0, 0);
    }

    #pragma unroll
    for (int pt = 0; pt < 2; ++pt) {
      #pragma unroll
      for (int r = 0; r < 4; ++r) {
        float p0 = 0.f, p1 = 0.f;
        #pragma unroll
        for (int nt = 0; nt < 4; ++nt) {
          float z = fmaxf(acc[pt][nt][r] + b1v[nt], 0.f);
          p0 += z * w20v[nt];
          p1 += z * w21v[nt];
        }
        p0 += __shfl_xor(p0, 1); p1 += __shfl_xor(p1, 1);
        p0 += __shfl_xor(p0, 2); p1 += __shfl_xor(p1, 2);
        p0 += __shfl_xor(p0, 4); p1 += __shfl_xor(p1, 4);
        p0 += __shfl_xor(p0, 8); p1 += __shfl_xor(p1, 8);
        int pair = wbase + pt * 16 + lkg * 4 + r;
        if (lrow == 0 && pair < P) {
          float2 o = make_float2(p0 + bb0, p1 + bb1);
          *(float2*)(out + 2 * (size_t)pair) = o;
        }
      }
    }
  }
}

// ---------------- launch ----------------

extern "C" void kernel_launch(void* const* d_in, const int* in_sizes, int n_in,
                              void* d_out, int out_size, void* d_ws, size_t ws_size,
                              hipStream_t stream)
{
  (void)n_in; (void)out_size; (void)ws_size;
  const float* h   = (const float*)d_in[0];
  const int*   src = (const int*)d_in[1];
  const int*   dst = (const int*)d_in[2];
  const int*   x1  = (const int*)d_in[3];
  const int*   x2  = (const int*)d_in[4];
  const float* Ws0 = (const float*)d_in[5];
  const float* Wn0 = (const float*)d_in[6];
  const float* b0  = (const float*)d_in[7];
  const float* Ws1 = (const float*)d_in[8];
  const float* Wn1 = (const float*)d_in[9];
  const float* b1  = (const float*)d_in[10];
  const float* W1  = (const float*)d_in[11];
  const float* bl1 = (const float*)d_in[12];
  const float* W2  = (const float*)d_in[13];
  const float* bl2 = (const float*)d_in[14];

  const int N = in_sizes[0] / 64;
  const int E = in_sizes[1];
  const int P = in_sizes[3];
  const int B = (N + NPB - 1) >> BSH;
  float* out = (float*)d_out;

  const int NCH = (E + CHUNK - 1) / CHUNK;
  const int n8  = N * 64 / 8;

  char* ws = (char*)d_ws;
  size_t off = 0;
  auto carve = [&](size_t bytes) {
    char* p = ws + off;
    off = (off + bytes + 255) & ~(size_t)255;
    return p;
  };
  int*    row_ptr      = (int*)carve((size_t)(N + 1) * 4);
  int*    chunkHist    = (int*)carve((size_t)NCH * MAXB * 4);
  int*    bucketCnt    = (int*)carve(MAXB * 4);
  int*    bucketBase   = (int*)carve((MAXB + 1) * 4);
  int*    bucketCursor = (int*)carve(MAXB * 4);
  int*    csr_src  = (int*)carve((size_t)E * 4);
  ushort* h_bf     = (ushort*)carve((size_t)N * 64 * 2);
  ushort* m1       = (ushort*)carve((size_t)N * 64 * 2);
  ushort* m2       = (ushort*)carve((size_t)N * 64 * 2);
  int2*   stag     = (int2*)carve((size_t)E * 8);
  ushort* aggb     = (ushort*)carve((size_t)N * 64 * 2);
  ushort* w1t      = (ushort*)carve(64 * 200 * 2);
  ushort* wtS0     = (ushort*)carve(4096 * 2);
  ushort* wtN0     = (ushort*)carve(4096 * 2);
  ushort* wtS1     = (ushort*)carve(4096 * 2);
  ushort* wtN1     = (ushort*)carve(4096 * 2);

  k_prep<<<(n8 + 255) / 256, 256, 0, stream>>>(h, W1, Ws0, Wn0, Ws1, Wn1, dst,
                                               h_bf, w1t, wtS0, wtN0, wtS1, wtN1,
                                               chunkHist, n8, E, NCH);
  k_hsum<<<MAXB, 256, 0, stream>>>(chunkHist, bucketCnt, NCH);
  k_bscan<<<1, MAXB, 0, stream>>>(bucketCnt, bucketBase, bucketCursor, row_ptr, B, N, E);
  k_part <<<NCH, 256, 0, stream>>>(src, dst, bucketCursor, stag, E);
  k_csr_bucket<<<B, NPB, 0, stream>>>(stag, bucketBase, row_ptr, csr_src, N);

  const int nbW = (N + 3) / 4;
  const int nbX = (N + 127) / 128;   // 128 nodes per block (32/wave)

  k_agg_bf<<<nbW, 256, 0, stream>>>(h_bf, row_ptr, csr_src, aggb, N);
  k_xform_mfma<<<nbX, 256, 0, stream>>>(h_bf, aggb, wtS0, wtN0, b0, m1, N);
  k_agg_bf<<<nbW, 256, 0, stream>>>(m1, row_ptr, csr_src, aggb, N);
  k_xform_mfma<<<nbX, 256, 0, stream>>>(m1, aggb, wtS1, wtN1, b1, m2, N);

  const int nTiles = (P + 127) / 128;
  const int nbP = (nTiles < HEAD_BLOCKS) ? nTiles : HEAD_BLOCKS;
  k_head_mfma<<<nbP, 256, 0, stream>>>(m2, x1, x2, w1t, bl1, W2, bl2, out, P);
}

// Round 15
// 179.557 us; speedup vs baseline: 1.3225x; 1.0082x over previous
//
#include <hip/hip_runtime.h>
#include <hip/hip_bf16.h>

using s8v = __attribute__((ext_vector_type(8))) short;   // 8 bf16 (4 VGPRs)
using f4v = __attribute__((ext_vector_type(4))) float;   // MFMA accumulator

__device__ __forceinline__ float bf2f(ushort v) { return __uint_as_float(((unsigned)v) << 16); }
__device__ __forceinline__ ushort f2bf(float x) {
  unsigned u = __float_as_uint(x);
  return (ushort)((u + 0x7fffu + ((u >> 16) & 1u)) >> 16);   // RNE, matches numpy
}

// |x - y| for 8 bf16 elems, result bf16, via v_cvt_pk_bf16_f32 (RNE)
__device__ __forceinline__ s8v absdiff_bf(s8v x, s8v y) {
  s8v d;
  #pragma unroll
  for (int q = 0; q < 4; ++q) {
    float f0 = fabsf(bf2f((ushort)x[2*q+0]) - bf2f((ushort)y[2*q+0]));
    float f1 = fabsf(bf2f((ushort)x[2*q+1]) - bf2f((ushort)y[2*q+1]));
    unsigned w;
    asm("v_cvt_pk_bf16_f32 %0, %1, %2" : "=v"(w) : "v"(f0), "v"(f1));
    d[2*q+0] = (short)(w & 0xffffu);
    d[2*q+1] = (short)(w >> 16);
  }
  return d;
}

#define BSH 9                    // 512 nodes per bucket
#define NPB 512
#define MAXB 256                 // covers N <= 131072 (= 2^17, src fits 17 bits)
#define CHUNK 4096
#define HEAD_BLOCKS 1024         // persistent head grid (4 blocks/CU)

// ---------------- fused prep: cast h->bf16 + weight preps + per-chunk histogram ----------------

__global__ __launch_bounds__(256) void k_prep(
    const float* __restrict__ h, const float* __restrict__ W1,
    const float* __restrict__ Ws0, const float* __restrict__ Wn0,
    const float* __restrict__ Ws1, const float* __restrict__ Wn1,
    const int* __restrict__ dst,
    ushort* __restrict__ h_bf, ushort* __restrict__ w1t,
    ushort* __restrict__ tS0, ushort* __restrict__ tN0,
    ushort* __restrict__ tS1, ushort* __restrict__ tN1,
    int* __restrict__ chunkHist, int n8, int E, int nch)
{
  __shared__ int hh[MAXB];
  int t = threadIdx.x;
  int i = blockIdx.x * 256 + t;

  if (i < 4096) {            // layer weights -> bf16 transposed [j][k]
    int j = i >> 6, k = i & 63;
    int o = k * 64 + j;
    tS0[i] = f2bf(Ws0[o]);
    tN0[i] = f2bf(Wn0[o]);
    tS1[i] = f2bf(Ws1[o]);
    tN1[i] = f2bf(Wn1[o]);
  }
  if (i < 64 * 200) {        // W1 -> transposed bf16 [n][200], zero-padded
    int n = i / 200, k = i % 200;
    float v = (k < 192) ? W1[k * 64 + n] : 0.f;
    w1t[i] = f2bf(v);
  }
  if (i < n8) {              // h -> bf16, 8 elems/thread
    const float4* in4 = (const float4*)h;
    float4 va = in4[2 * i], vb = in4[2 * i + 1];
    s8v w;
    w[0] = (short)f2bf(va.x); w[1] = (short)f2bf(va.y);
    w[2] = (short)f2bf(va.z); w[3] = (short)f2bf(va.w);
    w[4] = (short)f2bf(vb.x); w[5] = (short)f2bf(vb.y);
    w[6] = (short)f2bf(vb.z); w[7] = (short)f2bf(vb.w);
    ((s8v*)h_bf)[i] = w;
  }
  if (blockIdx.x < (unsigned)nch) {   // bucket histogram for this chunk
    hh[t] = 0;
    __syncthreads();
    int base = blockIdx.x * CHUNK;
    #pragma unroll
    for (int k = 0; k < CHUNK / 256; ++k) {
      int e = base + k * 256 + t;
      if (e < E) atomicAdd(&hh[dst[e] >> BSH], 1);
    }
    __syncthreads();
    chunkHist[blockIdx.x * MAXB + t] = hh[t];
  }
}

// ---------------- phase 1b: parallel reduction of chunk histograms ----------------

__global__ __launch_bounds__(256) void k_hsum(const int* __restrict__ chunkHist,
                                              int* __restrict__ bucketCnt, int nch) {
  __shared__ int sh[256];
  int b = blockIdx.x;
  int t = threadIdx.x;
  int v = 0;
  for (int c = t; c < nch; c += 256) v += chunkHist[c * MAXB + b];
  sh[t] = v;
  __syncthreads();
  for (int o = 128; o > 0; o >>= 1) {
    if (t < o) sh[t] += sh[t + o];
    __syncthreads();
  }
  if (t == 0) bucketCnt[b] = sh[0];
}

// ---------------- phase 2: scan buckets -> base & cursor ----------------

__global__ __launch_bounds__(256) void k_bscan(const int* __restrict__ bucketCnt,
                                               int* __restrict__ bucketBase,
                                               int* __restrict__ bucketCursor,
                                               int* __restrict__ row_ptr,
                                               int B, int N, int E) {
  __shared__ int sh[MAXB];
  int t = threadIdx.x;
  int v = (t < B) ? bucketCnt[t] : 0;
  sh[t] = v;
  __syncthreads();
  for (int off = 1; off < MAXB; off <<= 1) {
    int y = (t >= off) ? sh[t - off] : 0;
    __syncthreads();
    sh[t] += y;
    __syncthreads();
  }
  int excl = sh[t] - v;
  if (t < B) { bucketBase[t] = excl; bucketCursor[t] = excl; }
  if (t == 0) { bucketBase[B] = E; row_ptr[N] = E; }
}

// ---------------- phase 3: partition edges into bucket-grouped staging ----------------
// Staging entry packed to 4B: src (17 bits) | (dst & 511) << 17.

__global__ __launch_bounds__(256) void k_part(
    const int* __restrict__ src, const int* __restrict__ dst,
    int* __restrict__ bucketCursor, unsigned* __restrict__ stag, int E)
{
  __shared__ int hh[MAXB];     // local hist
  __shared__ int sc[MAXB];     // local exclusive scan
  __shared__ int cur[MAXB];    // placement cursor
  __shared__ int gb[MAXB];     // global base for this block's run
  __shared__ int2 pairs[CHUNK];

  int t = threadIdx.x;
  int base = blockIdx.x * CHUNK;
  int M = E - base; if (M > CHUNK) M = CHUNK;

  int es[CHUNK / 256], ed[CHUNK / 256];
  #pragma unroll
  for (int k = 0; k < CHUNK / 256; ++k) {
    int e = base + k * 256 + t;
    if (e < E) { es[k] = src[e]; ed[k] = dst[e]; } else { ed[k] = -1; }
  }

  hh[t] = 0;
  __syncthreads();
  #pragma unroll
  for (int k = 0; k < CHUNK / 256; ++k)
    if (ed[k] >= 0) atomicAdd(&hh[ed[k] >> BSH], 1);
  __syncthreads();

  // exclusive scan of hh[0..256) with 256 threads
  int v = hh[t];
  sc[t] = v;
  __syncthreads();
  for (int off = 1; off < MAXB; off <<= 1) {
    int y = (t >= off) ? sc[t - off] : 0;
    __syncthreads();
    sc[t] += y;
    __syncthreads();
  }
  int excl = sc[t] - v;
  sc[t] = excl;
  cur[t] = excl;
  if (v) gb[t] = atomicAdd(&bucketCursor[t], v);
  __syncthreads();

  // place pairs bucket-major into LDS
  #pragma unroll
  for (int k = 0; k < CHUNK / 256; ++k)
    if (ed[k] >= 0) {
      int b = ed[k] >> BSH;
      int pos = atomicAdd(&cur[b], 1);
      pairs[pos] = make_int2(es[k], ed[k]);
    }
  __syncthreads();

  // write out packed: slot s of bucket b -> stag[gb[b] + s - sc[b]]
  for (int s = t; s < M; s += 256) {
    int2 pr = pairs[s];
    int b = pr.y >> BSH;
    unsigned u = (unsigned)pr.x | ((unsigned)(pr.y & (NPB - 1)) << 17);
    stag[gb[b] + s - sc[b]] = u;
  }
}

// ---------------- phase 4: per-bucket CSR finalize (packed staging) ----------------

__global__ __launch_bounds__(512) void k_csr_bucket(
    const unsigned* __restrict__ stag, const int* __restrict__ bucketBase,
    int* __restrict__ row_ptr, int* __restrict__ csr_src, int N)
{
  __shared__ int dh[NPB], db[NPB], dc[NPB];
  int t = threadIdx.x;
  int b = blockIdx.x;
  int n0 = b << BSH;
  int nn = N - n0; if (nn > NPB) nn = NPB;
  int estart = bucketBase[b], eend = bucketBase[b + 1];

  dh[t] = 0;
  __syncthreads();
  for (int e = estart + t; e < eend; e += 512)
    atomicAdd(&dh[stag[e] >> 17], 1);
  __syncthreads();
  int v = dh[t];
  db[t] = v;
  __syncthreads();
  for (int off = 1; off < NPB; off <<= 1) {
    int y = (t >= off) ? db[t - off] : 0;
    __syncthreads();
    db[t] += y;
    __syncthreads();
  }
  int excl = db[t] - v;
  if (t < nn) row_ptr[n0 + t] = estart + excl;
  dc[t] = excl;
  __syncthreads();
  for (int e = estart + t; e < eend; e += 512) {
    unsigned u = stag[e];
    int d = u >> 17;
    int pos = estart + atomicAdd(&dc[d], 1);
    csr_src[pos] = (int)(u & 0x1FFFFu);
  }
}

// ---------------- aggregation: wave-per-node, 2x unrolled, LDS transpose-reduce ----------------

__global__ __launch_bounds__(256) void k_agg_bf(
    const ushort* __restrict__ fb, const int* __restrict__ rp,
    const int* __restrict__ csrc, ushort* __restrict__ agg, int N)
{
  __shared__ float red[4][512];
  int lane = threadIdx.x & 63;
  int wid  = threadIdx.x >> 6;
  int node = (blockIdx.x * 256 + threadIdx.x) >> 6;
  if (node >= N) return;
  int g  = lane >> 3;
  int c8 = (lane & 7) * 8;
  int e0 = rp[node], e1 = rp[node + 1];
  int len = e1 - e0;
  float a0=0.f,a1=0.f,a2=0.f,a3=0.f,a4=0.f,a5=0.f,a6=0.f,a7=0.f;
  int nfull = len >> 3;
  int it = 0;
  int e = e0;
  for (; it + 2 <= nfull; it += 2, e += 16) {
    int sA = csrc[e + g];
    int sB = csrc[e + 8 + g];
    s8v va = *(const s8v*)(fb + (size_t)sA * 64 + c8);
    s8v vb = *(const s8v*)(fb + (size_t)sB * 64 + c8);
    a0 += bf2f((ushort)va[0]); a1 += bf2f((ushort)va[1]);
    a2 += bf2f((ushort)va[2]); a3 += bf2f((ushort)va[3]);
    a4 += bf2f((ushort)va[4]); a5 += bf2f((ushort)va[5]);
    a6 += bf2f((ushort)va[6]); a7 += bf2f((ushort)va[7]);
    a0 += bf2f((ushort)vb[0]); a1 += bf2f((ushort)vb[1]);
    a2 += bf2f((ushort)vb[2]); a3 += bf2f((ushort)vb[3]);
    a4 += bf2f((ushort)vb[4]); a5 += bf2f((ushort)vb[5]);
    a6 += bf2f((ushort)vb[6]); a7 += bf2f((ushort)vb[7]);
  }
  if (it < nfull) {
    int s = csrc[e + g];
    s8v vv = *(const s8v*)(fb + (size_t)s * 64 + c8);
    a0 += bf2f((ushort)vv[0]); a1 += bf2f((ushort)vv[1]);
    a2 += bf2f((ushort)vv[2]); a3 += bf2f((ushort)vv[3]);
    a4 += bf2f((ushort)vv[4]); a5 += bf2f((ushort)vv[5]);
    a6 += bf2f((ushort)vv[6]); a7 += bf2f((ushort)vv[7]);
    e += 8;
  }
  if (e + g < e1) {
    int s = csrc[e + g];
    s8v vv = *(const s8v*)(fb + (size_t)s * 64 + c8);
    a0 += bf2f((ushort)vv[0]); a1 += bf2f((ushort)vv[1]);
    a2 += bf2f((ushort)vv[2]); a3 += bf2f((ushort)vv[3]);
    a4 += bf2f((ushort)vv[4]); a5 += bf2f((ushort)vv[5]);
    a6 += bf2f((ushort)vv[6]); a7 += bf2f((ushort)vv[7]);
  }

  // LDS transpose-reduce
  float* rw = &red[wid][0];
  float4 w0 = make_float4(a0, a1, a2, a3);
  float4 w1 = make_float4(a4, a5, a6, a7);
  *(float4*)(rw + lane * 8 + 0) = w0;
  *(float4*)(rw + lane * 8 + 4) = w1;
  float s = 0.f;
  #pragma unroll
  for (int g2 = 0; g2 < 8; ++g2) s += rw[g2 * 64 + lane];
  float inv = 1.f / (float)(len > 0 ? len : 1);
  agg[(size_t)node * 64 + lane] = f2bf(s * inv);
}

// ---------------- layer transform via MFMA: 32 nodes/wave ----------------

__global__ __launch_bounds__(256) void k_xform_mfma(
    const ushort* __restrict__ fb, const ushort* __restrict__ ab,
    const ushort* __restrict__ wtS, const ushort* __restrict__ wtN,
    const float* __restrict__ bias, ushort* __restrict__ outb, int N)
{
  int lane = threadIdx.x & 63;
  int wid  = threadIdx.x >> 6;
  int wbase = blockIdx.x * 128 + wid * 32;
  if (wbase >= N) return;
  int lrow = lane & 15;
  int lkg  = lane >> 4;

  s8v bS[4][2], bN[4][2];
  #pragma unroll
  for (int nt = 0; nt < 4; ++nt) {
    #pragma unroll
    for (int ks = 0; ks < 2; ++ks) {
      int o = (nt * 16 + lrow) * 64 + ks * 32 + lkg * 8;
      bS[nt][ks] = *(const s8v*)(wtS + o);
      bN[nt][ks] = *(const s8v*)(wtN + o);
    }
  }

  f4v acc[2][4];
  #pragma unroll
  for (int a = 0; a < 2; ++a)
    #pragma unroll
    for (int b = 0; b < 4; ++b)
      acc[a][b] = (f4v){0.f, 0.f, 0.f, 0.f};

  #pragma unroll
  for (int pt = 0; pt < 2; ++pt) {
    int node = wbase + pt * 16 + lrow;
    int nc = (node < N) ? node : (N - 1);
    const ushort* fr = fb + (size_t)nc * 64 + lkg * 8;
    const ushort* ar = ab + (size_t)nc * 64 + lkg * 8;
    s8v f0 = *(const s8v*)(fr);
    s8v f1 = *(const s8v*)(fr + 32);
    s8v g0 = *(const s8v*)(ar);
    s8v g1 = *(const s8v*)(ar + 32);
    #pragma unroll
    for (int nt = 0; nt < 4; ++nt) {
      acc[pt][nt] = __builtin_amdgcn_mfma_f32_16x16x32_bf16(f0, bS[nt][0], acc[pt][nt], 0, 0, 0);
      acc[pt][nt] = __builtin_amdgcn_mfma_f32_16x16x32_bf16(f1, bS[nt][1], acc[pt][nt], 0, 0, 0);
      acc[pt][nt] = __builtin_amdgcn_mfma_f32_16x16x32_bf16(g0, bN[nt][0], acc[pt][nt], 0, 0, 0);
      acc[pt][nt] = __builtin_amdgcn_mfma_f32_16x16x32_bf16(g1, bN[nt][1], acc[pt][nt], 0, 0, 0);
    }
  }

  float bv[4];
  #pragma unroll
  for (int nt = 0; nt < 4; ++nt) bv[nt] = bias[nt * 16 + lrow];

  #pragma unroll
  for (int pt = 0; pt < 2; ++pt) {
    #pragma unroll
    for (int r = 0; r < 4; ++r) {
      int node = wbase + pt * 16 + lkg * 4 + r;
      if (node < N) {
        ushort* orow = outb + (size_t)node * 64;
        #pragma unroll
        for (int nt = 0; nt < 4; ++nt) {
          float z = fmaxf(acc[pt][nt][r] + bv[nt], 0.f);
          orow[nt * 16 + lrow] = f2bf(z);
        }
      }
    }
  }
}

// ---------------- head via MFMA: persistent blocks, W staged ONCE per block ----------------

__global__ __launch_bounds__(256) void k_head_mfma(
    const ushort* __restrict__ hb, const int* __restrict__ x1, const int* __restrict__ x2,
    const ushort* __restrict__ w1t, const float* __restrict__ bl1,
    const float* __restrict__ W2, const float* __restrict__ bl2,
    float* __restrict__ out, int P)
{
  __shared__ __align__(16) ushort sW[64 * 200];
  __shared__ float sW2[128];
  __shared__ float sb1[64];
  __shared__ float sb2[2];
  {
    const float4* srcv = (const float4*)w1t;
    float4* dstv = (float4*)sW;
    for (int i = threadIdx.x; i < 1600; i += 256) dstv[i] = srcv[i];
    if (threadIdx.x < 128) sW2[threadIdx.x] = W2[threadIdx.x];
    if (threadIdx.x < 64)  sb1[threadIdx.x] = bl1[threadIdx.x];
    if (threadIdx.x < 2)   sb2[threadIdx.x] = bl2[threadIdx.x];
  }
  __syncthreads();

  int lane = threadIdx.x & 63;
  int wid  = threadIdx.x >> 6;
  int lrow = lane & 15;
  int lkg  = lane >> 4;

  float b1v[4], w20v[4], w21v[4];
  #pragma unroll
  for (int nt = 0; nt < 4; ++nt) {
    int n = nt * 16 + lrow;
    b1v[nt] = sb1[n];
    w20v[nt] = sW2[2 * n + 0];
    w21v[nt] = sW2[2 * n + 1];
  }
  float bb0 = sb2[0], bb1 = sb2[1];

  int nTiles = (P + 127) / 128;
  for (int tile = blockIdx.x; tile < nTiles; tile += gridDim.x) {
    int wbase = tile * 128 + wid * 32;   // 32 pairs per wave
    if (wbase >= P) continue;

    int pa = wbase + lrow;
    int pb = wbase + 16 + lrow;
    int pca = (pa < P) ? pa : (P - 1);
    int pcb = (pb < P) ? pb : (P - 1);
    int i1a = x1[pca], i2a = x2[pca];
    int i1b = x1[pcb], i2b = x2[pcb];
    const ushort* r1a = hb + (size_t)i1a * 64 + lkg * 8;
    const ushort* r2a = hb + (size_t)i2a * 64 + lkg * 8;
    const ushort* r1b = hb + (size_t)i1b * 64 + lkg * 8;
    const ushort* r2b = hb + (size_t)i2b * 64 + lkg * 8;
    s8v a1a0 = *(const s8v*)(r1a);
    s8v a1a1 = *(const s8v*)(r1a + 32);
    s8v a2a0 = *(const s8v*)(r2a);
    s8v a2a1 = *(const s8v*)(r2a + 32);
    s8v a1b0 = *(const s8v*)(r1b);
    s8v a1b1 = *(const s8v*)(r1b + 32);
    s8v a2b0 = *(const s8v*)(r2b);
    s8v a2b1 = *(const s8v*)(r2b + 32);

    s8v da0 = absdiff_bf(a1a0, a2a0);
    s8v da1 = absdiff_bf(a1a1, a2a1);
    s8v db0 = absdiff_bf(a1b0, a2b0);
    s8v db1 = absdiff_bf(a1b1, a2b1);

    f4v acc[2][4];
    #pragma unroll
    for (int a = 0; a < 2; ++a)
      #pragma unroll
      for (int b = 0; b < 4; ++b)
        acc[a][b] = (f4v){0.f, 0.f, 0.f, 0.f};

    #pragma unroll
    for (int nt = 0; nt < 4; ++nt) {
      const ushort* bw = &sW[(nt * 16 + lrow) * 200 + lkg * 8];
      s8v b1_0 = *(const s8v*)(bw + 0);
      s8v b2_0 = *(const s8v*)(bw + 64);
      s8v b3_0 = *(const s8v*)(bw + 128);
      acc[0][nt] = __builtin_amdgcn_mfma_f32_16x16x32_bf16(a1a0, b1_0, acc[0][nt], 0, 0, 0);
      acc[0][nt] = __builtin_amdgcn_mfma_f32_16x16x32_bf16(a2a0, b2_0, acc[0][nt], 0, 0, 0);
      acc[0][nt] = __builtin_amdgcn_mfma_f32_16x16x32_bf16(da0,  b3_0, acc[0][nt], 0, 0, 0);
      acc[1][nt] = __builtin_amdgcn_mfma_f32_16x16x32_bf16(a1b0, b1_0, acc[1][nt], 0, 0, 0);
      acc[1][nt] = __builtin_amdgcn_mfma_f32_16x16x32_bf16(a2b0, b2_0, acc[1][nt], 0, 0, 0);
      acc[1][nt] = __builtin_amdgcn_mfma_f32_16x16x32_bf16(db0,  b3_0, acc[1][nt], 0, 0, 0);
      s8v b1_1 = *(const s8v*)(bw + 32);
      s8v b2_1 = *(const s8v*)(bw + 96);
      s8v b3_1 = *(const s8v*)(bw + 160);
      acc[0][nt] = __builtin_amdgcn_mfma_f32_16x16x32_bf16(a1a1, b1_1, acc[0][nt], 0, 0, 0);
      acc[0][nt] = __builtin_amdgcn_mfma_f32_16x16x32_bf16(a2a1, b2_1, acc[0][nt], 0, 0, 0);
      acc[0][nt] = __builtin_amdgcn_mfma_f32_16x16x32_bf16(da1,  b3_1, acc[0][nt], 0, 0, 0);
      acc[1][nt] = __builtin_amdgcn_mfma_f32_16x16x32_bf16(a1b1, b1_1, acc[1][nt], 0, 0, 0);
      acc[1][nt] = __builtin_amdgcn_mfma_f32_16x16x32_bf16(a2b1, b2_1, acc[1][nt], 0, 0, 0);
      acc[1][nt] = __builtin_amdgcn_mfma_f32_16x16x32_bf16(db1,  b3_1, acc[1][nt], 0, 0, 0);
    }

    #pragma unroll
    for (int pt = 0; pt < 2; ++pt) {
      #pragma unroll
      for (int r = 0; r < 4; ++r) {
        float p0 = 0.f, p1 = 0.f;
        #pragma unroll
        for (int nt = 0; nt < 4; ++nt) {
          float z = fmaxf(acc[pt][nt][r] + b1v[nt], 0.f);
          p0 += z * w20v[nt];
          p1 += z * w21v[nt];
        }
        p0 += __shfl_xor(p0, 1); p1 += __shfl_xor(p1, 1);
        p0 += __shfl_xor(p0, 2); p1 += __shfl_xor(p1, 2);
        p0 += __shfl_xor(p0, 4); p1 += __shfl_xor(p1, 4);
        p0 += __shfl_xor(p0, 8); p1 += __shfl_xor(p1, 8);
        int pair = wbase + pt * 16 + lkg * 4 + r;
        if (lrow == 0 && pair < P) {
          float2 o = make_float2(p0 + bb0, p1 + bb1);
          *(float2*)(out + 2 * (size_t)pair) = o;
        }
      }
    }
  }
}

// ---------------- launch ----------------

extern "C" void kernel_launch(void* const* d_in, const int* in_sizes, int n_in,
                              void* d_out, int out_size, void* d_ws, size_t ws_size,
                              hipStream_t stream)
{
  (void)n_in; (void)out_size; (void)ws_size;
  const float* h   = (const float*)d_in[0];
  const int*   src = (const int*)d_in[1];
  const int*   dst = (const int*)d_in[2];
  const int*   x1  = (const int*)d_in[3];
  const int*   x2  = (const int*)d_in[4];
  const float* Ws0 = (const float*)d_in[5];
  const float* Wn0 = (const float*)d_in[6];
  const float* b0  = (const float*)d_in[7];
  const float* Ws1 = (const float*)d_in[8];
  const float* Wn1 = (const float*)d_in[9];
  const float* b1  = (const float*)d_in[10];
  const float* W1  = (const float*)d_in[11];
  const float* bl1 = (const float*)d_in[12];
  const float* W2  = (const float*)d_in[13];
  const float* bl2 = (const float*)d_in[14];

  const int N = in_sizes[0] / 64;
  const int E = in_sizes[1];
  const int P = in_sizes[3];
  const int B = (N + NPB - 1) >> BSH;
  float* out = (float*)d_out;

  const int NCH = (E + CHUNK - 1) / CHUNK;
  const int n8  = N * 64 / 8;

  char* ws = (char*)d_ws;
  size_t off = 0;
  auto carve = [&](size_t bytes) {
    char* p = ws + off;
    off = (off + bytes + 255) & ~(size_t)255;
    return p;
  };
  int*      row_ptr      = (int*)carve((size_t)(N + 1) * 4);
  int*      chunkHist    = (int*)carve((size_t)NCH * MAXB * 4);
  int*      bucketCnt    = (int*)carve(MAXB * 4);
  int*      bucketBase   = (int*)carve((MAXB + 1) * 4);
  int*      bucketCursor = (int*)carve(MAXB * 4);
  int*      csr_src  = (int*)carve((size_t)E * 4);
  ushort*   h_bf     = (ushort*)carve((size_t)N * 64 * 2);
  ushort*   m1       = (ushort*)carve((size_t)N * 64 * 2);
  ushort*   m2       = (ushort*)carve((size_t)N * 64 * 2);
  unsigned* stag     = (unsigned*)carve((size_t)E * 4);
  ushort*   aggb     = (ushort*)carve((size_t)N * 64 * 2);
  ushort*   w1t      = (ushort*)carve(64 * 200 * 2);
  ushort*   wtS0     = (ushort*)carve(4096 * 2);
  ushort*   wtN0     = (ushort*)carve(4096 * 2);
  ushort*   wtS1     = (ushort*)carve(4096 * 2);
  ushort*   wtN1     = (ushort*)carve(4096 * 2);

  k_prep<<<(n8 + 255) / 256, 256, 0, stream>>>(h, W1, Ws0, Wn0, Ws1, Wn1, dst,
                                               h_bf, w1t, wtS0, wtN0, wtS1, wtN1,
                                               chunkHist, n8, E, NCH);
  k_hsum<<<MAXB, 256, 0, stream>>>(chunkHist, bucketCnt, NCH);
  k_bscan<<<1, MAXB, 0, stream>>>(bucketCnt, bucketBase, bucketCursor, row_ptr, B, N, E);
  k_part <<<NCH, 256, 0, stream>>>(src, dst, bucketCursor, stag, E);
  k_csr_bucket<<<B, NPB, 0, stream>>>(stag, bucketBase, row_ptr, csr_src, N);

  const int nbW = (N + 3) / 4;
  const int nbX = (N + 127) / 128;   // 128 nodes per block (32/wave)

  k_agg_bf<<<nbW, 256, 0, stream>>>(h_bf, row_ptr, csr_src, aggb, N);
  k_xform_mfma<<<nbX, 256, 0, stream>>>(h_bf, aggb, wtS0, wtN0, b0, m1, N);
  k_agg_bf<<<nbW, 256, 0, stream>>>(m1, row_ptr, csr_src, aggb, N);
  k_xform_mfma<<<nbX, 256, 0, stream>>>(m1, aggb, wtS1, wtN1, b1, m2, N);

  const int nTiles = (P + 127) / 128;
  const int nbP = (nTiles < HEAD_BLOCKS) ? nTiles : HEAD_BLOCKS;
  k_head_mfma<<<nbP, 256, 0, stream>>>(m2, x1, x2, w1t, bl1, W2, bl2, out, P);
}